// Round 1
// baseline (878.912 us; speedup 1.0000x reference)
//
#include <hip/hip_runtime.h>
#include <hip/hip_bf16.h>
#include <cstdint>
#include <cstddef>

// Problem constants
#define NMEM 16
#define DDIM 512
#define BATCH 4
#define LSEQ 4096
#define ROWS 16384      // BATCH*LSEQ
#define NCAND 16
#define KTOP 8

typedef __attribute__((ext_vector_type(8))) short bf16x8;
typedef __attribute__((ext_vector_type(4))) float f32x4;

__device__ inline unsigned short f2bf(float f) {
    unsigned int u = __float_as_uint(f);
    unsigned int r = (u + 0x7fffu + ((u >> 16) & 1u)) >> 16;
    return (unsigned short)r;
}

__device__ inline void gld16(const void* gptr, void* lptr) {
    __builtin_amdgcn_global_load_lds(
        (const __attribute__((address_space(1))) unsigned int*)gptr,
        (__attribute__((address_space(3))) unsigned int*)lptr,
        16, 0, 0);
}

__device__ inline float fast_tanh(float p) {
    p = fminf(fmaxf(p, -15.f), 15.f);
    float e = __expf(2.f * p);
    return (e - 1.f) / (e + 1.f);
}

// ---------- conversion kernels ----------
__global__ void convert_q_kernel(const float* __restrict__ in,
                                 unsigned short* __restrict__ out, int nElem) {
    int i = (blockIdx.x * 256 + threadIdx.x) * 4;
    if (i < nElem) {
        float4 v = *(const float4*)(in + i);
        ushort4 o;
        o.x = f2bf(v.x); o.y = f2bf(v.y); o.z = f2bf(v.z); o.w = f2bf(v.w);
        *(ushort4*)(out + i) = o;
    }
}

// in: [16][512][512] row-major (d, j); out: [16][512][512] with out[n][j][d] = in[n][d][j]
__global__ void transpose_w_kernel(const float* __restrict__ in,
                                   unsigned short* __restrict__ out) {
    __shared__ float t[32][33];
    int n = blockIdx.z;
    int d0 = blockIdx.y * 32, j0 = blockIdx.x * 32;
    const float* inN = in + (size_t)n * DDIM * DDIM;
    unsigned short* outN = out + (size_t)n * DDIM * DDIM;
    int tx = threadIdx.x, ty = threadIdx.y;   // 32 x 8
    for (int r = 0; r < 32; r += 8)
        t[ty + r][tx] = inN[(size_t)(d0 + ty + r) * DDIM + j0 + tx];
    __syncthreads();
    for (int r = 0; r < 32; r += 8)
        outN[(size_t)(j0 + ty + r) * DDIM + d0 + tx] = f2bf(t[tx][ty + r]);
}

// ---------- GEMM 1: H = leaky(Q @ W1 + b1), bf16 out ----------
// grid (4, 128, z) ; block 256 (4 waves, 2x2 wave grid, 64x64/wave, 4x4 frags)
__global__ __launch_bounds__(256, 2)
void gemm1_kernel(const unsigned short* __restrict__ Qb,    // [16384][512] bf16
                  const unsigned short* __restrict__ W1T,   // [16][512][512] bf16 (j-major)
                  const float* __restrict__ b1,             // [16][512]
                  unsigned short* __restrict__ H,           // [z][16384][512] bf16
                  int slot0)
{
    __shared__ unsigned short As[128 * 64];
    __shared__ unsigned short Bs[128 * 64];
    const int n  = slot0 + blockIdx.z;
    const int m0 = blockIdx.y * 128;
    const int n0 = blockIdx.x * 128;
    const int tid  = threadIdx.x;
    const int lane = tid & 63;
    const int w    = tid >> 6;
    const int wm   = (w >> 1) * 64;
    const int wn   = (w & 1) * 64;
    const unsigned short* Ag = Qb + (size_t)m0 * DDIM;
    const unsigned short* Bg = W1T + ((size_t)n * DDIM + n0) * DDIM;

    f32x4 acc[4][4] = {};

    for (int kt = 0; kt < DDIM; kt += 64) {
        #pragma unroll
        for (int i = 0; i < 4; ++i) {
            int c = i * 256 + tid;            // lane-contiguous per wave
            int row = c >> 3, k8 = (c & 7) * 8;
            gld16(Ag + (size_t)row * DDIM + kt + k8, &As[c * 8]);
            gld16(Bg + (size_t)row * DDIM + kt + k8, &Bs[c * 8]);
        }
        __syncthreads();
        const int r = lane & 15, q8 = (lane >> 4) * 8;
        #pragma unroll
        for (int ks = 0; ks < 64; ks += 32) {
            bf16x8 a[4], b[4];
            #pragma unroll
            for (int f = 0; f < 4; ++f) {
                a[f] = *(const bf16x8*)&As[(wm + f * 16 + r) * 64 + ks + q8];
                b[f] = *(const bf16x8*)&Bs[(wn + f * 16 + r) * 64 + ks + q8];
            }
            #pragma unroll
            for (int fr = 0; fr < 4; ++fr)
                #pragma unroll
                for (int fc = 0; fc < 4; ++fc)
                    acc[fr][fc] = __builtin_amdgcn_mfma_f32_16x16x32_bf16(
                        a[fr], b[fc], acc[fr][fc], 0, 0, 0);
        }
        __syncthreads();
    }

    const float slope = 0.01f + 0.0125f * n;
    unsigned short* Hout = H + (size_t)blockIdx.z * ((size_t)ROWS * DDIM);
    const int colr = lane & 15, quad = lane >> 4;
    #pragma unroll
    for (int fc = 0; fc < 4; ++fc) {
        int col = n0 + wn + fc * 16 + colr;
        float bias = b1[n * DDIM + col];
        #pragma unroll
        for (int fr = 0; fr < 4; ++fr) {
            int rowb = m0 + wm + fr * 16 + quad * 4;
            #pragma unroll
            for (int rg = 0; rg < 4; ++rg) {
                float h = acc[fr][fc][rg] + bias;
                h = h >= 0.f ? h : h * slope;
                Hout[(size_t)(rowb + rg) * DDIM + col] = f2bf(h);
            }
        }
    }
}

// ---------- GEMM 2: logits += (tanh(H @ W2 + b2)) . Wg  (atomic per row) ----------
__global__ __launch_bounds__(256, 2)
void gemm2_kernel(const unsigned short* __restrict__ H,     // [z][16384][512] bf16
                  const unsigned short* __restrict__ W2T,   // [16][512][512] bf16
                  const float* __restrict__ b2,             // [16][512]
                  const float* __restrict__ Wg,             // [16][512]
                  float* __restrict__ logits,               // [16][16384]
                  int slot0)
{
    __shared__ unsigned short As[128 * 64];
    __shared__ unsigned short Bs[128 * 64];
    const int n  = slot0 + blockIdx.z;
    const int m0 = blockIdx.y * 128;
    const int n0 = blockIdx.x * 128;
    const int tid  = threadIdx.x;
    const int lane = tid & 63;
    const int w    = tid >> 6;
    const int wm   = (w >> 1) * 64;
    const int wn   = (w & 1) * 64;
    const unsigned short* Ag = H + (size_t)blockIdx.z * ((size_t)ROWS * DDIM) + (size_t)m0 * DDIM;
    const unsigned short* Bg = W2T + ((size_t)n * DDIM + n0) * DDIM;

    f32x4 acc[4][4] = {};

    for (int kt = 0; kt < DDIM; kt += 64) {
        #pragma unroll
        for (int i = 0; i < 4; ++i) {
            int c = i * 256 + tid;
            int row = c >> 3, k8 = (c & 7) * 8;
            gld16(Ag + (size_t)row * DDIM + kt + k8, &As[c * 8]);
            gld16(Bg + (size_t)row * DDIM + kt + k8, &Bs[c * 8]);
        }
        __syncthreads();
        const int r = lane & 15, q8 = (lane >> 4) * 8;
        #pragma unroll
        for (int ks = 0; ks < 64; ks += 32) {
            bf16x8 a[4], b[4];
            #pragma unroll
            for (int f = 0; f < 4; ++f) {
                a[f] = *(const bf16x8*)&As[(wm + f * 16 + r) * 64 + ks + q8];
                b[f] = *(const bf16x8*)&Bs[(wn + f * 16 + r) * 64 + ks + q8];
            }
            #pragma unroll
            for (int fr = 0; fr < 4; ++fr)
                #pragma unroll
                for (int fc = 0; fc < 4; ++fc)
                    acc[fr][fc] = __builtin_amdgcn_mfma_f32_16x16x32_bf16(
                        a[fr], b[fc], acc[fr][fc], 0, 0, 0);
        }
        __syncthreads();
    }

    // Epilogue: tanh, dot with Wg along cols, reduce over 16 lanes per row, atomicAdd
    const int colr = lane & 15, quad = lane >> 4;
    float wgv[4], b2v[4];
    #pragma unroll
    for (int fc = 0; fc < 4; ++fc) {
        int col = n0 + wn + fc * 16 + colr;
        wgv[fc] = Wg[n * DDIM + col];
        b2v[fc] = b2[n * DDIM + col];
    }
    float rowsum[4][4];
    #pragma unroll
    for (int fr = 0; fr < 4; ++fr)
        #pragma unroll
        for (int rg = 0; rg < 4; ++rg) {
            float s = 0.f;
            #pragma unroll
            for (int fc = 0; fc < 4; ++fc) {
                float x = fast_tanh(acc[fr][fc][rg] + b2v[fc]);
                s = fmaf(x, wgv[fc], s);
            }
            rowsum[fr][rg] = s;
        }
    #pragma unroll
    for (int sh = 1; sh < 16; sh <<= 1)
        #pragma unroll
        for (int fr = 0; fr < 4; ++fr)
            #pragma unroll
            for (int rg = 0; rg < 4; ++rg)
                rowsum[fr][rg] += __shfl_xor(rowsum[fr][rg], sh);
    if (colr == 0) {
        float* Ln = logits + (size_t)n * ROWS;
        #pragma unroll
        for (int fr = 0; fr < 4; ++fr) {
            int rowb = m0 + wm + fr * 16 + quad * 4;
            #pragma unroll
            for (int rg = 0; rg < 4; ++rg)
                atomicAdd(&Ln[rowb + rg], rowsum[fr][rg]);
        }
    }
}

// ---------- top-16 candidates per (n,b) by approx logits ----------
__global__ __launch_bounds__(256)
void topcand_kernel(const float* __restrict__ logits, int* __restrict__ cand) {
    __shared__ float vals[LSEQ];
    __shared__ float rv[256];
    __shared__ int   ri[256];
    int p = blockIdx.x;            // p = n*4 + b
    int n = p >> 2, b = p & 3;
    const float* L = logits + (size_t)n * ROWS + (size_t)b * LSEQ;
    for (int i = threadIdx.x; i < LSEQ; i += 256) vals[i] = L[i];
    __syncthreads();
    for (int r = 0; r < NCAND; ++r) {
        float best = -1e30f; int bi = 0x7fffffff;
        for (int i = threadIdx.x; i < LSEQ; i += 256) {
            float v = vals[i];
            if (v > best) { best = v; bi = i; }
        }
        rv[threadIdx.x] = best; ri[threadIdx.x] = bi;
        __syncthreads();
        for (int s = 128; s > 0; s >>= 1) {
            if (threadIdx.x < s) {
                float ov = rv[threadIdx.x + s]; int oi = ri[threadIdx.x + s];
                if (ov > rv[threadIdx.x] ||
                    (ov == rv[threadIdx.x] && oi < ri[threadIdx.x])) {
                    rv[threadIdx.x] = ov; ri[threadIdx.x] = oi;
                }
            }
            __syncthreads();
        }
        if (threadIdx.x == 0) { cand[p * NCAND + r] = ri[0]; vals[ri[0]] = -1e30f; }
        __syncthreads();
    }
}

// ---------- exact fp32 recompute at candidates ----------
// grid 64 (one per (n,b)), block 512: thread t owns output dim j=t, all 16 candidates
__global__ __launch_bounds__(512)
void exact_kernel(const float* __restrict__ query,  // [4][4096][512] f32
                  const float* __restrict__ W1, const float* __restrict__ b1,
                  const float* __restrict__ W2, const float* __restrict__ b2,
                  const float* __restrict__ Wg,
                  const int* __restrict__ cand,
                  float* __restrict__ ex_x,         // [64][16][512]
                  float* __restrict__ ex_logit)     // [64][16] (pre-zeroed)
{
    __shared__ float qs[NCAND][DDIM];
    __shared__ float hs[NCAND][DDIM];
    int p = blockIdx.x; int n = p >> 2, b = p & 3;
    for (int c = 0; c < NCAND; ++c) {
        int li = cand[p * NCAND + c];
        const float* qr = query + ((size_t)b * LSEQ + li) * DDIM;
        for (int d = threadIdx.x; d < DDIM; d += 512) qs[c][d] = qr[d];
    }
    __syncthreads();
    const float slope = 0.01f + 0.0125f * n;
    const float* W1n = W1 + (size_t)n * DDIM * DDIM;
    const float* W2n = W2 + (size_t)n * DDIM * DDIM;
    int j = threadIdx.x;
    {
        float a[NCAND];
        float bb = b1[n * DDIM + j];
        #pragma unroll
        for (int c = 0; c < NCAND; ++c) a[c] = bb;
        for (int d = 0; d < DDIM; ++d) {
            float wv = W1n[(size_t)d * DDIM + j];
            #pragma unroll
            for (int c = 0; c < NCAND; ++c) a[c] = fmaf(qs[c][d], wv, a[c]);
        }
        #pragma unroll
        for (int c = 0; c < NCAND; ++c) {
            float h = a[c];
            hs[c][j] = h >= 0.f ? h : h * slope;
        }
    }
    __syncthreads();
    {
        float a[NCAND];
        float bb = b2[n * DDIM + j];
        #pragma unroll
        for (int c = 0; c < NCAND; ++c) a[c] = bb;
        for (int d = 0; d < DDIM; ++d) {
            float wv = W2n[(size_t)d * DDIM + j];
            #pragma unroll
            for (int c = 0; c < NCAND; ++c) a[c] = fmaf(hs[c][d], wv, a[c]);
        }
        float wg = Wg[n * DDIM + j];
        float lp[NCAND];
        #pragma unroll
        for (int c = 0; c < NCAND; ++c) {
            float x = tanhf(a[c]);
            ex_x[((size_t)p * NCAND + c) * DDIM + j] = x;
            lp[c] = x * wg;
        }
        #pragma unroll
        for (int c = 0; c < NCAND; ++c) {
            float v = lp[c];
            #pragma unroll
            for (int s = 1; s < 64; s <<= 1) v += __shfl_xor(v, s);
            if ((threadIdx.x & 63) == 0) atomicAdd(&ex_logit[p * NCAND + c], v);
        }
    }
}

// ---------- final: exact top-8, weight, combine, normalize ----------
__global__ __launch_bounds__(64)
void final_kernel(const float* __restrict__ ex_x, const float* __restrict__ ex_logit,
                  const int* __restrict__ cand, float* __restrict__ out)
{
    __shared__ float w8[KTOP];
    __shared__ int   s8[KTOP];
    int p = blockIdx.x; int n = p >> 2, b = p & 3;
    if (threadIdx.x == 0) {
        float lv[NCAND];
        for (int c = 0; c < NCAND; ++c) lv[c] = ex_logit[p * NCAND + c];
        unsigned int mask = 0;
        float lmax = 0.f;
        int sel[KTOP];
        for (int k = 0; k < KTOP; ++k) {
            float best = 0.f; int bi = -1;
            for (int c = 0; c < NCAND; ++c) {
                if (mask & (1u << c)) continue;
                float v = lv[c];
                if (bi < 0 || v > best ||
                    (v == best && cand[p * NCAND + c] < cand[p * NCAND + bi])) {
                    best = v; bi = c;
                }
            }
            mask |= (1u << bi); sel[k] = bi;
            if (k == 0) lmax = best;
        }
        for (int k = 0; k < KTOP; ++k) {
            w8[k] = expf(lv[sel[k]] - lmax);
            s8[k] = sel[k];
        }
    }
    __syncthreads();
    float cv[8];
    float sq = 0.f;
    int idx = 0;
    for (int d = threadIdx.x; d < DDIM; d += 64, ++idx) {
        float s = 0.f;
        #pragma unroll
        for (int k = 0; k < KTOP; ++k)
            s = fmaf(w8[k], ex_x[((size_t)p * NCAND + s8[k]) * DDIM + d], s);
        cv[idx] = s;
        sq += s * s;
    }
    #pragma unroll
    for (int s = 1; s < 64; s <<= 1) sq += __shfl_xor(sq, s);
    float norm = fmaxf(sqrtf(sq), 1e-12f);
    idx = 0;
    for (int d = threadIdx.x; d < DDIM; d += 64, ++idx)
        out[((size_t)b * NMEM + n) * DDIM + d] = cv[idx] / norm;
}

extern "C" void kernel_launch(void* const* d_in, const int* in_sizes, int n_in,
                              void* d_out, int out_size, void* d_ws, size_t ws_size,
                              hipStream_t stream)
{
    const float* query = (const float*)d_in[0];
    const float* W1    = (const float*)d_in[1];
    const float* b1    = (const float*)d_in[2];
    const float* W2    = (const float*)d_in[3];
    const float* b2    = (const float*)d_in[4];
    const float* Wg    = (const float*)d_in[5];
    // d_in[6] = bg: cancels under softmax + normalize; d_in[7] = topk (hardcoded 8)

    char* ws = (char*)d_ws;
    const size_t MB = 1024 * 1024;
    unsigned short* Qb  = (unsigned short*)(ws);                 // 16 MB
    unsigned short* W1T = (unsigned short*)(ws + 16 * MB);       // 8 MB
    unsigned short* W2T = (unsigned short*)(ws + 24 * MB);       // 8 MB
    float* logits   = (float*)(ws + 32 * MB);                    // 1 MB
    float* ex_logit = (float*)(ws + 33 * MB);                    // 4 KB
    int*   cand     = (int*)  (ws + 33 * MB + 4096);             // 4 KB
    float* ex_x     = (float*)(ws + 33 * MB + 8192);             // 2 MB
    unsigned short* H = (unsigned short*)(ws + 36 * MB);         // 256 MB (full) or 16 MB (per-slot)

    const size_t hFull = (size_t)NMEM * ROWS * DDIM * sizeof(unsigned short);
    bool full = ws_size >= 36 * MB + hFull;

    // zero atomic targets (logits 1MB + ex_logit 4KB, contiguous)
    hipMemsetAsync(logits, 0, MB + 4096, stream);

    convert_q_kernel<<<8192, 256, 0, stream>>>(query, Qb, ROWS * DDIM);
    dim3 tb(32, 8);
    transpose_w_kernel<<<dim3(16, 16, 16), tb, 0, stream>>>(W1, W1T);
    transpose_w_kernel<<<dim3(16, 16, 16), tb, 0, stream>>>(W2, W2T);

    if (full) {
        gemm1_kernel<<<dim3(4, 128, 16), 256, 0, stream>>>(Qb, W1T, b1, H, 0);
        gemm2_kernel<<<dim3(4, 128, 16), 256, 0, stream>>>(H, W2T, b2, Wg, logits, 0);
    } else {
        for (int s = 0; s < NMEM; ++s) {
            gemm1_kernel<<<dim3(4, 128, 1), 256, 0, stream>>>(Qb, W1T, b1, H, s);
            gemm2_kernel<<<dim3(4, 128, 1), 256, 0, stream>>>(H, W2T, b2, Wg, logits, s);
        }
    }

    topcand_kernel<<<64, 256, 0, stream>>>(logits, cand);
    exact_kernel<<<64, 512, 0, stream>>>(query, W1, b1, W2, b2, Wg, cand, ex_x, ex_logit);
    final_kernel<<<64, 64, 0, stream>>>(ex_x, ex_logit, cand, (float*)d_out);
}

// Round 2
// 667.198 us; speedup vs baseline: 1.3173x; 1.3173x over previous
//
#include <hip/hip_runtime.h>
#include <hip/hip_bf16.h>
#include <cstdint>
#include <cstddef>

// Problem constants
#define NMEM 16
#define DDIM 512
#define BATCH 4
#define LSEQ 4096
#define ROWS 16384      // BATCH*LSEQ
#define NCAND 16
#define KTOP 8
#define QPAD 20         // [d][c] LDS leading-dim pad: 16-B aligned, 8-way-max bank spread

typedef __attribute__((ext_vector_type(8))) short bf16x8;
typedef __attribute__((ext_vector_type(4))) float f32x4;

__device__ inline unsigned short f2bf(float f) {
    unsigned int u = __float_as_uint(f);
    unsigned int r = (u + 0x7fffu + ((u >> 16) & 1u)) >> 16;
    return (unsigned short)r;
}

__device__ inline void gld16(const void* gptr, void* lptr) {
    __builtin_amdgcn_global_load_lds(
        (const __attribute__((address_space(1))) unsigned int*)gptr,
        (__attribute__((address_space(3))) unsigned int*)lptr,
        16, 0, 0);
}

__device__ inline float fast_tanh(float p) {
    p = fminf(fmaxf(p, -15.f), 15.f);
    float e = __expf(2.f * p);
    return (e - 1.f) / (e + 1.f);
}

// ---------- conversion kernels ----------
__global__ void convert_q_kernel(const float* __restrict__ in,
                                 unsigned short* __restrict__ out, int nElem) {
    int i = (blockIdx.x * 256 + threadIdx.x) * 4;
    if (i < nElem) {
        float4 v = *(const float4*)(in + i);
        ushort4 o;
        o.x = f2bf(v.x); o.y = f2bf(v.y); o.z = f2bf(v.z); o.w = f2bf(v.w);
        *(ushort4*)(out + i) = o;
    }
}

// in: [16][512][512] (d, j); out[n][j][d] = in[n][d][j]  (bf16)
__global__ void transpose_w_kernel(const float* __restrict__ in,
                                   unsigned short* __restrict__ out) {
    __shared__ float t[32][33];
    int n = blockIdx.z;
    int d0 = blockIdx.y * 32, j0 = blockIdx.x * 32;
    const float* inN = in + (size_t)n * DDIM * DDIM;
    unsigned short* outN = out + (size_t)n * DDIM * DDIM;
    int tx = threadIdx.x, ty = threadIdx.y;   // 32 x 8
    for (int r = 0; r < 32; r += 8)
        t[ty + r][tx] = inN[(size_t)(d0 + ty + r) * DDIM + j0 + tx];
    __syncthreads();
    for (int r = 0; r < 32; r += 8)
        outN[(size_t)(j0 + ty + r) * DDIM + d0 + tx] = f2bf(t[tx][ty + r]);
}

// ---------- GEMM 1: H = leaky(Q @ W1 + b1), bf16 out ----------
__global__ __launch_bounds__(256, 2)
void gemm1_kernel(const unsigned short* __restrict__ Qb,    // [16384][512] bf16
                  const unsigned short* __restrict__ W1T,   // [16][512][512] bf16 (j-major)
                  const float* __restrict__ b1,             // [16][512]
                  unsigned short* __restrict__ H,           // [z][16384][512] bf16
                  int slot0)
{
    __shared__ unsigned short As[128 * 64];
    __shared__ unsigned short Bs[128 * 64];
    const int n  = slot0 + blockIdx.z;
    const int m0 = blockIdx.y * 128;
    const int n0 = blockIdx.x * 128;
    const int tid  = threadIdx.x;
    const int lane = tid & 63;
    const int w    = tid >> 6;
    const int wm   = (w >> 1) * 64;
    const int wn   = (w & 1) * 64;
    const unsigned short* Ag = Qb + (size_t)m0 * DDIM;
    const unsigned short* Bg = W1T + ((size_t)n * DDIM + n0) * DDIM;

    f32x4 acc[4][4] = {};

    for (int kt = 0; kt < DDIM; kt += 64) {
        #pragma unroll
        for (int i = 0; i < 4; ++i) {
            int c = i * 256 + tid;            // lane-contiguous per wave
            int row = c >> 3, k8 = (c & 7) * 8;
            gld16(Ag + (size_t)row * DDIM + kt + k8, &As[c * 8]);
            gld16(Bg + (size_t)row * DDIM + kt + k8, &Bs[c * 8]);
        }
        __syncthreads();
        const int r = lane & 15, q8 = (lane >> 4) * 8;
        #pragma unroll
        for (int ks = 0; ks < 64; ks += 32) {
            bf16x8 a[4], b[4];
            #pragma unroll
            for (int f = 0; f < 4; ++f) {
                a[f] = *(const bf16x8*)&As[(wm + f * 16 + r) * 64 + ks + q8];
                b[f] = *(const bf16x8*)&Bs[(wn + f * 16 + r) * 64 + ks + q8];
            }
            #pragma unroll
            for (int fr = 0; fr < 4; ++fr)
                #pragma unroll
                for (int fc = 0; fc < 4; ++fc)
                    acc[fr][fc] = __builtin_amdgcn_mfma_f32_16x16x32_bf16(
                        a[fr], b[fc], acc[fr][fc], 0, 0, 0);
        }
        __syncthreads();
    }

    const float slope = 0.01f + 0.0125f * n;
    unsigned short* Hout = H + (size_t)blockIdx.z * ((size_t)ROWS * DDIM);
    const int colr = lane & 15, quad = lane >> 4;
    #pragma unroll
    for (int fc = 0; fc < 4; ++fc) {
        int col = n0 + wn + fc * 16 + colr;
        float bias = b1[n * DDIM + col];
        #pragma unroll
        for (int fr = 0; fr < 4; ++fr) {
            int rowb = m0 + wm + fr * 16 + quad * 4;
            #pragma unroll
            for (int rg = 0; rg < 4; ++rg) {
                float h = acc[fr][fc][rg] + bias;
                h = h >= 0.f ? h : h * slope;
                Hout[(size_t)(rowb + rg) * DDIM + col] = f2bf(h);
            }
        }
    }
}

// ---------- GEMM 2: logits += (tanh(H @ W2 + b2)) . Wg ----------
__global__ __launch_bounds__(256, 2)
void gemm2_kernel(const unsigned short* __restrict__ H,
                  const unsigned short* __restrict__ W2T,
                  const float* __restrict__ b2,
                  const float* __restrict__ Wg,
                  float* __restrict__ logits,               // [16][16384]
                  int slot0)
{
    __shared__ unsigned short As[128 * 64];
    __shared__ unsigned short Bs[128 * 64];
    const int n  = slot0 + blockIdx.z;
    const int m0 = blockIdx.y * 128;
    const int n0 = blockIdx.x * 128;
    const int tid  = threadIdx.x;
    const int lane = tid & 63;
    const int w    = tid >> 6;
    const int wm   = (w >> 1) * 64;
    const int wn   = (w & 1) * 64;
    const unsigned short* Ag = H + (size_t)blockIdx.z * ((size_t)ROWS * DDIM) + (size_t)m0 * DDIM;
    const unsigned short* Bg = W2T + ((size_t)n * DDIM + n0) * DDIM;

    f32x4 acc[4][4] = {};

    for (int kt = 0; kt < DDIM; kt += 64) {
        #pragma unroll
        for (int i = 0; i < 4; ++i) {
            int c = i * 256 + tid;
            int row = c >> 3, k8 = (c & 7) * 8;
            gld16(Ag + (size_t)row * DDIM + kt + k8, &As[c * 8]);
            gld16(Bg + (size_t)row * DDIM + kt + k8, &Bs[c * 8]);
        }
        __syncthreads();
        const int r = lane & 15, q8 = (lane >> 4) * 8;
        #pragma unroll
        for (int ks = 0; ks < 64; ks += 32) {
            bf16x8 a[4], b[4];
            #pragma unroll
            for (int f = 0; f < 4; ++f) {
                a[f] = *(const bf16x8*)&As[(wm + f * 16 + r) * 64 + ks + q8];
                b[f] = *(const bf16x8*)&Bs[(wn + f * 16 + r) * 64 + ks + q8];
            }
            #pragma unroll
            for (int fr = 0; fr < 4; ++fr)
                #pragma unroll
                for (int fc = 0; fc < 4; ++fc)
                    acc[fr][fc] = __builtin_amdgcn_mfma_f32_16x16x32_bf16(
                        a[fr], b[fc], acc[fr][fc], 0, 0, 0);
        }
        __syncthreads();
    }

    const int colr = lane & 15, quad = lane >> 4;
    float wgv[4], b2v[4];
    #pragma unroll
    for (int fc = 0; fc < 4; ++fc) {
        int col = n0 + wn + fc * 16 + colr;
        wgv[fc] = Wg[n * DDIM + col];
        b2v[fc] = b2[n * DDIM + col];
    }
    float rowsum[4][4];
    #pragma unroll
    for (int fr = 0; fr < 4; ++fr)
        #pragma unroll
        for (int rg = 0; rg < 4; ++rg) {
            float s = 0.f;
            #pragma unroll
            for (int fc = 0; fc < 4; ++fc) {
                float x = fast_tanh(acc[fr][fc][rg] + b2v[fc]);
                s = fmaf(x, wgv[fc], s);
            }
            rowsum[fr][rg] = s;
        }
    #pragma unroll
    for (int sh = 1; sh < 16; sh <<= 1)
        #pragma unroll
        for (int fr = 0; fr < 4; ++fr)
            #pragma unroll
            for (int rg = 0; rg < 4; ++rg)
                rowsum[fr][rg] += __shfl_xor(rowsum[fr][rg], sh);
    if (colr == 0) {
        float* Ln = logits + (size_t)n * ROWS;
        #pragma unroll
        for (int fr = 0; fr < 4; ++fr) {
            int rowb = m0 + wm + fr * 16 + quad * 4;
            #pragma unroll
            for (int rg = 0; rg < 4; ++rg)
                atomicAdd(&Ln[rowb + rg], rowsum[fr][rg]);
        }
    }
}

// ---------- topcand phase A: per (p, quarter) top-16 of 1024 ----------
__global__ __launch_bounds__(256)
void topcandA_kernel(const float* __restrict__ logits,
                     float* __restrict__ tcv, int* __restrict__ tci) {
    __shared__ float vals[1024];
    __shared__ float wv[4];
    __shared__ int   wi[4];
    int blk = blockIdx.x;           // p*4 + q
    int p = blk >> 2, q = blk & 3;
    int n = p >> 2, b = p & 3;
    const float* L = logits + (size_t)n * ROWS + (size_t)b * LSEQ + q * 1024;
    int t = threadIdx.x;
    for (int i = t; i < 1024; i += 256) vals[i] = L[i];
    __syncthreads();
    for (int r = 0; r < NCAND; ++r) {
        float best = -1e30f; int bi = 0x7fffffff;
        for (int i = t; i < 1024; i += 256) {
            float v = vals[i];
            if (v > best || (v == best && i < bi)) { best = v; bi = i; }
        }
        #pragma unroll
        for (int s = 1; s < 64; s <<= 1) {
            float ov = __shfl_xor(best, s); int oi = __shfl_xor(bi, s);
            if (ov > best || (ov == best && oi < bi)) { best = ov; bi = oi; }
        }
        if ((t & 63) == 0) { wv[t >> 6] = best; wi[t >> 6] = bi; }
        __syncthreads();
        if (t == 0) {
            float bb = wv[0]; int bbi = wi[0];
            for (int w2 = 1; w2 < 4; ++w2)
                if (wv[w2] > bb || (wv[w2] == bb && wi[w2] < bbi)) { bb = wv[w2]; bbi = wi[w2]; }
            tcv[blk * NCAND + r] = bb;
            tci[blk * NCAND + r] = q * 1024 + bbi;
            vals[bbi] = -1e30f;
        }
        __syncthreads();
    }
}

// ---------- topcand phase B: merge 4x16 -> top-16 ----------
__global__ __launch_bounds__(64)
void topcandB_kernel(const float* __restrict__ tcv, const int* __restrict__ tci,
                     int* __restrict__ cand) {
    int p = blockIdx.x, t = threadIdx.x;
    float v = tcv[p * 64 + t];
    int idx = tci[p * 64 + t];
    for (int r = 0; r < NCAND; ++r) {
        float best = v; int bi = idx;
        #pragma unroll
        for (int s = 1; s < 64; s <<= 1) {
            float ov = __shfl_xor(best, s); int oi = __shfl_xor(bi, s);
            if (ov > best || (ov == best && oi < bi)) { best = ov; bi = oi; }
        }
        if (t == 0) cand[p * NCAND + r] = bi;
        if (idx == bi) v = -1e30f;
    }
}

// ---------- exact phase 1: h at candidates (fp32) ----------
// grid 64p x 8jc = 512 blocks, 256 thr: thread (jj=t&63, dg=t>>6), j=jc*64+jj
__global__ __launch_bounds__(256)
void exact_h_kernel(const float* __restrict__ query,
                    const float* __restrict__ W1, const float* __restrict__ b1,
                    const int* __restrict__ cand, float* __restrict__ ex_h) {
    __shared__ float qs[DDIM][QPAD];        // [d][c], 40 KB
    __shared__ float hpart[4][NCAND][64];   // 16 KB
    int p = blockIdx.x >> 3, jc = blockIdx.x & 7;
    int n = p >> 2, b = p & 3;
    int t = threadIdx.x, jj = t & 63, dg = t >> 6;
    int j = jc * 64 + jj;
    for (int c = 0; c < NCAND; ++c) {
        int li = cand[p * NCAND + c];
        const float* qr = query + ((size_t)b * LSEQ + li) * DDIM;
        for (int d = t; d < DDIM; d += 256) qs[d][c] = qr[d];
    }
    __syncthreads();
    const float* W1n = W1 + (size_t)n * DDIM * DDIM;
    float acc[NCAND] = {};
    for (int d = dg * 128; d < dg * 128 + 128; ++d) {
        float wvv = W1n[(size_t)d * DDIM + j];
        const float4* qv = (const float4*)&qs[d][0];   // same-addr b128 broadcast
        #pragma unroll
        for (int c4 = 0; c4 < 4; ++c4) {
            float4 q4 = qv[c4];
            acc[c4 * 4 + 0] = fmaf(q4.x, wvv, acc[c4 * 4 + 0]);
            acc[c4 * 4 + 1] = fmaf(q4.y, wvv, acc[c4 * 4 + 1]);
            acc[c4 * 4 + 2] = fmaf(q4.z, wvv, acc[c4 * 4 + 2]);
            acc[c4 * 4 + 3] = fmaf(q4.w, wvv, acc[c4 * 4 + 3]);
        }
    }
    #pragma unroll
    for (int c = 0; c < NCAND; ++c) hpart[dg][c][jj] = acc[c];
    __syncthreads();
    const float slope = 0.01f + 0.0125f * n;
    float bias = b1[n * DDIM + j];
    for (int cc = dg; cc < NCAND; cc += 4) {
        float h = hpart[0][cc][jj] + hpart[1][cc][jj] + hpart[2][cc][jj]
                + hpart[3][cc][jj] + bias;
        h = h >= 0.f ? h : h * slope;
        ex_h[((size_t)p * NCAND + cc) * DDIM + j] = h;
    }
}

// ---------- exact phase 2: x + exact logits ----------
__global__ __launch_bounds__(256)
void exact_x_kernel(const float* __restrict__ ex_h,
                    const float* __restrict__ W2, const float* __restrict__ b2,
                    const float* __restrict__ Wg,
                    float* __restrict__ ex_x, float* __restrict__ ex_logit) {
    __shared__ float hs[DDIM][QPAD];
    __shared__ float xpart[4][NCAND][64];
    int p = blockIdx.x >> 3, jc = blockIdx.x & 7;
    int n = p >> 2;
    int t = threadIdx.x, jj = t & 63, dg = t >> 6;
    int j = jc * 64 + jj;
    for (int c = 0; c < NCAND; ++c) {
        const float* hr = ex_h + ((size_t)p * NCAND + c) * DDIM;
        for (int d = t; d < DDIM; d += 256) hs[d][c] = hr[d];
    }
    __syncthreads();
    const float* W2n = W2 + (size_t)n * DDIM * DDIM;
    float acc[NCAND] = {};
    for (int d = dg * 128; d < dg * 128 + 128; ++d) {
        float wvv = W2n[(size_t)d * DDIM + j];
        const float4* hv = (const float4*)&hs[d][0];
        #pragma unroll
        for (int c4 = 0; c4 < 4; ++c4) {
            float4 h4 = hv[c4];
            acc[c4 * 4 + 0] = fmaf(h4.x, wvv, acc[c4 * 4 + 0]);
            acc[c4 * 4 + 1] = fmaf(h4.y, wvv, acc[c4 * 4 + 1]);
            acc[c4 * 4 + 2] = fmaf(h4.z, wvv, acc[c4 * 4 + 2]);
            acc[c4 * 4 + 3] = fmaf(h4.w, wvv, acc[c4 * 4 + 3]);
        }
    }
    #pragma unroll
    for (int c = 0; c < NCAND; ++c) xpart[dg][c][jj] = acc[c];
    __syncthreads();
    float bias = b2[n * DDIM + j];
    float wg = Wg[n * DDIM + j];
    // wave dg handles cands cc = dg, dg+4, dg+8, dg+12 (all 64 jj in one wave)
    for (int cc = dg; cc < NCAND; cc += 4) {
        float a = xpart[0][cc][jj] + xpart[1][cc][jj] + xpart[2][cc][jj]
                + xpart[3][cc][jj] + bias;
        float x = tanhf(a);
        ex_x[((size_t)p * NCAND + cc) * DDIM + j] = x;
        float lp = x * wg;
        #pragma unroll
        for (int s = 1; s < 64; s <<= 1) lp += __shfl_xor(lp, s);
        if (jj == 0) atomicAdd(&ex_logit[p * NCAND + cc], lp);
    }
}

// ---------- final: exact top-8, weight, combine, normalize ----------
__global__ __launch_bounds__(64)
void final_kernel(const float* __restrict__ ex_x, const float* __restrict__ ex_logit,
                  const int* __restrict__ cand, float* __restrict__ out)
{
    __shared__ float w8[KTOP];
    __shared__ int   s8[KTOP];
    int p = blockIdx.x; int n = p >> 2, b = p & 3;
    if (threadIdx.x == 0) {
        float lv[NCAND];
        for (int c = 0; c < NCAND; ++c) lv[c] = ex_logit[p * NCAND + c];
        unsigned int mask = 0;
        float lmax = 0.f;
        int sel[KTOP];
        for (int k = 0; k < KTOP; ++k) {
            float best = 0.f; int bi = -1;
            for (int c = 0; c < NCAND; ++c) {
                if (mask & (1u << c)) continue;
                float v = lv[c];
                if (bi < 0 || v > best ||
                    (v == best && cand[p * NCAND + c] < cand[p * NCAND + bi])) {
                    best = v; bi = c;
                }
            }
            mask |= (1u << bi); sel[k] = bi;
            if (k == 0) lmax = best;
        }
        for (int k = 0; k < KTOP; ++k) {
            w8[k] = expf(lv[sel[k]] - lmax);
            s8[k] = sel[k];
        }
    }
    __syncthreads();
    float cv[8];
    float sq = 0.f;
    int idx = 0;
    for (int d = threadIdx.x; d < DDIM; d += 64, ++idx) {
        float s = 0.f;
        #pragma unroll
        for (int k = 0; k < KTOP; ++k)
            s = fmaf(w8[k], ex_x[((size_t)p * NCAND + s8[k]) * DDIM + d], s);
        cv[idx] = s;
        sq += s * s;
    }
    #pragma unroll
    for (int s = 1; s < 64; s <<= 1) sq += __shfl_xor(sq, s);
    float norm = fmaxf(sqrtf(sq), 1e-12f);
    idx = 0;
    for (int d = threadIdx.x; d < DDIM; d += 64, ++idx)
        out[((size_t)b * NMEM + n) * DDIM + d] = cv[idx] / norm;
}

extern "C" void kernel_launch(void* const* d_in, const int* in_sizes, int n_in,
                              void* d_out, int out_size, void* d_ws, size_t ws_size,
                              hipStream_t stream)
{
    const float* query = (const float*)d_in[0];
    const float* W1    = (const float*)d_in[1];
    const float* b1    = (const float*)d_in[2];
    const float* W2    = (const float*)d_in[3];
    const float* b2    = (const float*)d_in[4];
    const float* Wg    = (const float*)d_in[5];
    // d_in[6] = bg cancels under softmax+normalize; d_in[7] = topk (hardcoded 8)

    char* ws = (char*)d_ws;
    const size_t MB = 1024 * 1024;
    // Persistent-through-gemm region:
    unsigned short* Qb  = (unsigned short*)(ws);                 // 0..16 MB
    unsigned short* W1T = (unsigned short*)(ws + 16 * MB);       // 16..24
    unsigned short* W2T = (unsigned short*)(ws + 24 * MB);       // 24..32
    float* logits   = (float*)(ws + 32 * MB);                    // 32..33 (1 MB)
    // Post-gemm scratch reuses the (dead) Qb region:
    float* ex_h     = (float*)(ws);                              // 0..2 MB
    float* ex_x     = (float*)(ws + 2 * MB);                     // 2..4 MB
    float* ex_logit = (float*)(ws + 4 * MB);                     // 4 KB
    int*   cand     = (int*)  (ws + 4 * MB + 4096);              // 4 KB
    float* tcv      = (float*)(ws + 4 * MB + 8192);              // 16 KB
    int*   tci      = (int*)  (ws + 4 * MB + 8192 + 16384);      // 16 KB
    unsigned short* H = (unsigned short*)(ws + 36 * MB);         // g x 16 MB

    // Largest slot-group that fits: needs 36 MB + g*16 MB (g=1 tier == proven R1 footprint)
    int g = 1;
    if      (ws_size >= 36 * MB + 256 * MB) g = 16;
    else if (ws_size >= 36 * MB + 128 * MB) g = 8;
    else if (ws_size >= 36 * MB +  64 * MB) g = 4;
    else if (ws_size >= 36 * MB +  32 * MB) g = 2;

    hipMemsetAsync(logits, 0, MB, stream);

    convert_q_kernel<<<8192, 256, 0, stream>>>(query, Qb, ROWS * DDIM);
    dim3 tb(32, 8);
    transpose_w_kernel<<<dim3(16, 16, 16), tb, 0, stream>>>(W1, W1T);
    transpose_w_kernel<<<dim3(16, 16, 16), tb, 0, stream>>>(W2, W2T);

    for (int s0 = 0; s0 < NMEM; s0 += g) {
        gemm1_kernel<<<dim3(4, 128, g), 256, 0, stream>>>(Qb, W1T, b1, H, s0);
        gemm2_kernel<<<dim3(4, 128, g), 256, 0, stream>>>(H, W2T, b2, Wg, logits, s0);
    }

    // Qb region is dead from here on
    hipMemsetAsync(ex_logit, 0, 4096, stream);
    topcandA_kernel<<<256, 256, 0, stream>>>(logits, tcv, tci);
    topcandB_kernel<<<64, 64, 0, stream>>>(tcv, tci, cand);
    exact_h_kernel<<<512, 256, 0, stream>>>(query, W1, b1, cand, ex_h);
    exact_x_kernel<<<512, 256, 0, stream>>>(ex_h, W2, b2, Wg, ex_x, ex_logit);
    final_kernel<<<64, 64, 0, stream>>>(ex_x, ex_logit, cand, (float*)d_out);
}

// Round 4
// 666.458 us; speedup vs baseline: 1.3188x; 1.0011x over previous
//
#include <hip/hip_runtime.h>
#include <hip/hip_bf16.h>
#include <cstdint>
#include <cstddef>

// Problem constants
#define NMEM 16
#define DDIM 512
#define BATCH 4
#define LSEQ 4096
#define ROWS 16384      // BATCH*LSEQ
#define NCAND 64        // fp8-noise safety: rank-8..64 gap ~4.6 sigma
#define KTOP 8
#define QPAD 20

typedef __attribute__((ext_vector_type(4))) float f32x4;
typedef __attribute__((ext_vector_type(8))) int int8v;

#if defined(__has_builtin)
#if __has_builtin(__builtin_amdgcn_mfma_scale_f32_16x16x128_f8f6f4)
#define HAS_MX 1
#endif
#endif

__device__ inline void gld16(const void* gptr, void* lptr) {
    __builtin_amdgcn_global_load_lds(
        (const __attribute__((address_space(1))) unsigned int*)gptr,
        (__attribute__((address_space(3))) unsigned int*)lptr,
        16, 0, 0);
}

__device__ inline float fast_tanh(float p) {
    p = fminf(fmaxf(p, -15.f), 15.f);
    float e = __expf(2.f * p);
    return (e - 1.f) / (e + 1.f);
}

// MX frag: lane holds k = (lane>>4)*32 + j (32 bytes, 2 swizzled b128 chunks)
__device__ inline int8v load_frag(const unsigned char* Ts, int row, int g, int hs) {
    int h = (row >> hs) & 7;
    const int4* p0 = (const int4*)(Ts + row * 128 + (((2 * g) ^ h) << 4));
    const int4* p1 = (const int4*)(Ts + row * 128 + (((2 * g + 1) ^ h) << 4));
    int4 x = *p0, y = *p1;
    int8v v;
    v[0] = x.x; v[1] = x.y; v[2] = x.z; v[3] = x.w;
    v[4] = y.x; v[5] = y.y; v[6] = y.z; v[7] = y.w;
    return v;
}
// fallback (K=32 instr): lane holds 8 bytes, chunk8 index c8
__device__ inline long long load_frag8(const unsigned char* Ts, int row, int c8, int hs) {
    int h = (row >> hs) & 7;
    return *(const long long*)(Ts + row * 128 + ((((c8 >> 1) ^ h) << 4) + ((c8 & 1) << 3)));
}

// ---------- fused prep: Q->fp8, W1/W2 transpose->fp8, zero logits ----------
// grid: 2048 (Q) + 1024 (W1) + 1024 (W2) + 256 (logits zero) = 4352
__global__ __launch_bounds__(256)
void prep_kernel(const float* __restrict__ query,
                 const float* __restrict__ W1, const float* __restrict__ W2,
                 unsigned char* __restrict__ Q8,
                 unsigned char* __restrict__ W1T8, unsigned char* __restrict__ W2T8,
                 float* __restrict__ logits) {
    int blk = blockIdx.x, t = threadIdx.x;
    if (blk < 2048) {                       // Q convert: 16 els/thread
        size_t base = ((size_t)blk * 256 + t) * 16;
        const float4* in = (const float4*)(query + base);
        int4 o; int* op = (int*)&o;
        #pragma unroll
        for (int q = 0; q < 4; ++q) {
            float4 v = in[q];
            int lo = __builtin_amdgcn_cvt_pk_fp8_f32(v.x, v.y, 0, false);
            op[q] = __builtin_amdgcn_cvt_pk_fp8_f32(v.z, v.w, lo, true);
        }
        *(int4*)(Q8 + base) = o;
    } else if (blk < 4096) {                // W transpose+convert, 64x64 tiles
        __shared__ float tile[64][69];
        int bid = blk - 2048;               // 0..2047: 1024 per matrix
        const float* Win = W1; unsigned char* Wout = W1T8;
        if (bid >= 1024) { bid -= 1024; Win = W2; Wout = W2T8; }
        int n = bid >> 6, t64 = bid & 63;   // n in [0,16), 64 tiles of 64x64
        int dt = (t64 >> 3) << 6, jt = (t64 & 7) << 6;
        const float* inN = Win + (size_t)n * DDIM * DDIM;
        unsigned char* outN = Wout + (size_t)n * DDIM * DDIM;
        int rr = t >> 4, cc = (t & 15) * 4;
        #pragma unroll
        for (int pass = 0; pass < 4; ++pass) {
            int row = rr + pass * 16;
            float4 v = *(const float4*)(inN + (size_t)(dt + row) * DDIM + jt + cc);
            tile[row][cc] = v.x; tile[row][cc + 1] = v.y;
            tile[row][cc + 2] = v.z; tile[row][cc + 3] = v.w;
        }
        __syncthreads();
        #pragma unroll
        for (int pass = 0; pass < 4; ++pass) {
            int jl = rr + pass * 16;
            float f0 = tile[cc][jl], f1 = tile[cc + 1][jl];
            float f2 = tile[cc + 2][jl], f3 = tile[cc + 3][jl];
            int lo = __builtin_amdgcn_cvt_pk_fp8_f32(f0, f1, 0, false);
            int dw = __builtin_amdgcn_cvt_pk_fp8_f32(f2, f3, lo, true);
            *(int*)(outN + (size_t)(jt + jl) * DDIM + dt + cc) = dw;
        }
    } else {                                // zero logits (1 MB)
        int bid = blk - 4096;               // 0..255
        ((int4*)logits)[bid * 256 + t] = int4{0, 0, 0, 0};
    }
}

// ---------- GEMM 1: H = leaky(Q @ W1 + b1), fp8 out ----------
// B-rows permuted (col = wn + colr*4 + fc) so epilogue packs 4 consecutive fp8 bytes
__global__ __launch_bounds__(256, 2)
void gemm1_kernel(const unsigned char* __restrict__ Q8,
                  const unsigned char* __restrict__ W1T8,
                  const float* __restrict__ b1,
                  unsigned char* __restrict__ H, int slot0)
{
    __shared__ unsigned char As[128 * 128];
    __shared__ unsigned char Bs[128 * 128];
    const int n  = slot0 + blockIdx.z;
    const int m0 = blockIdx.y * 128;
    const int n0 = blockIdx.x * 128;
    const int tid = threadIdx.x, lane = tid & 63, w = tid >> 6;
    const int wm = (w >> 1) * 64, wn = (w & 1) * 64;
    const int r = lane & 15, g = lane >> 4;
    const unsigned char* Ag = Q8 + (size_t)m0 * DDIM;
    const unsigned char* Bg = W1T8 + ((size_t)n * DDIM + n0) * DDIM;

    f32x4 acc[4][4] = {};

    for (int kt = 0; kt < DDIM; kt += 128) {
        #pragma unroll
        for (int i = 0; i < 4; ++i) {
            int c = i * 256 + tid;
            int row = c >> 3, ch = c & 7;
            gld16(Ag + (size_t)row * DDIM + kt + ((ch ^ (row & 7)) << 4), &As[c * 16]);
            gld16(Bg + (size_t)row * DDIM + kt + ((ch ^ ((row >> 2) & 7)) << 4), &Bs[c * 16]);
        }
        __syncthreads();
#ifdef HAS_MX
        int8v a[4], b[4];
        #pragma unroll
        for (int f = 0; f < 4; ++f) {
            a[f] = load_frag(As, wm + f * 16 + r, g, 0);
            b[f] = load_frag(Bs, wn + r * 4 + f, g, 2);
        }
        #pragma unroll
        for (int fr = 0; fr < 4; ++fr)
            #pragma unroll
            for (int fc = 0; fc < 4; ++fc)
                acc[fr][fc] = __builtin_amdgcn_mfma_scale_f32_16x16x128_f8f6f4(
                    a[fr], b[fc], acc[fr][fc], 0, 0, 0, 0x7F7F7F7F, 0, 0x7F7F7F7F);
#else
        #pragma unroll
        for (int ks = 0; ks < 4; ++ks) {
            long long a8[4], b8[4];
            #pragma unroll
            for (int f = 0; f < 4; ++f) {
                a8[f] = load_frag8(As, wm + f * 16 + r, 4 * ks + g, 0);
                b8[f] = load_frag8(Bs, wn + r * 4 + f, 4 * ks + g, 2);
            }
            #pragma unroll
            for (int fr = 0; fr < 4; ++fr)
                #pragma unroll
                for (int fc = 0; fc < 4; ++fc)
                    acc[fr][fc] = __builtin_amdgcn_mfma_f32_16x16x32_fp8_fp8(
                        a8[fr], b8[fc], acc[fr][fc], 0, 0, 0);
        }
#endif
        __syncthreads();
    }

    const float slope = 0.01f + 0.0125f * n;
    const float4 b4 = *(const float4*)&b1[n * DDIM + n0 + wn + r * 4];
    unsigned char* tile = As;   // reuse As as 16KB fp8 tile (post-barrier)
    #pragma unroll
    for (int fr = 0; fr < 4; ++fr) {
        #pragma unroll
        for (int rg = 0; rg < 4; ++rg) {
            int rr = wm + fr * 16 + g * 4 + rg;
            float v0 = acc[fr][0][rg] + b4.x; v0 = v0 >= 0.f ? v0 : v0 * slope;
            float v1 = acc[fr][1][rg] + b4.y; v1 = v1 >= 0.f ? v1 : v1 * slope;
            float v2 = acc[fr][2][rg] + b4.z; v2 = v2 >= 0.f ? v2 : v2 * slope;
            float v3 = acc[fr][3][rg] + b4.w; v3 = v3 >= 0.f ? v3 : v3 * slope;
            int lo = __builtin_amdgcn_cvt_pk_fp8_f32(v0, v1, 0, false);
            int dw = __builtin_amdgcn_cvt_pk_fp8_f32(v2, v3, lo, true);
            *(int*)(tile + rr * 128 + wn + r * 4) = dw;
        }
    }
    __syncthreads();
    unsigned char* Hout = H + (size_t)blockIdx.z * ((size_t)ROWS * DDIM)
                            + (size_t)m0 * DDIM + n0;
    #pragma unroll
    for (int i = 0; i < 4; ++i) {
        int c = i * 256 + tid;
        int row = c >> 3, ch = c & 7;
        *(int4*)(Hout + (size_t)row * DDIM + ch * 16) = *(const int4*)(tile + row * 128 + ch * 16);
    }
}

// ---------- GEMM 2: logits += (tanh(H @ W2 + b2)) . Wg ----------
__global__ __launch_bounds__(256, 2)
void gemm2_kernel(const unsigned char* __restrict__ H,
                  const unsigned char* __restrict__ W2T8,
                  const float* __restrict__ b2,
                  const float* __restrict__ Wg,
                  float* __restrict__ logits, int slot0)
{
    __shared__ unsigned char As[128 * 128];
    __shared__ unsigned char Bs[128 * 128];
    const int n  = slot0 + blockIdx.z;
    const int m0 = blockIdx.y * 128;
    const int n0 = blockIdx.x * 128;
    const int tid = threadIdx.x, lane = tid & 63, w = tid >> 6;
    const int wm = (w >> 1) * 64, wn = (w & 1) * 64;
    const int r = lane & 15, g = lane >> 4;
    const unsigned char* Ag = H + (size_t)blockIdx.z * ((size_t)ROWS * DDIM) + (size_t)m0 * DDIM;
    const unsigned char* Bg = W2T8 + ((size_t)n * DDIM + n0) * DDIM;

    f32x4 acc[4][4] = {};

    for (int kt = 0; kt < DDIM; kt += 128) {
        #pragma unroll
        for (int i = 0; i < 4; ++i) {
            int c = i * 256 + tid;
            int row = c >> 3, ch = c & 7;
            gld16(Ag + (size_t)row * DDIM + kt + ((ch ^ (row & 7)) << 4), &As[c * 16]);
            gld16(Bg + (size_t)row * DDIM + kt + ((ch ^ (row & 7)) << 4), &Bs[c * 16]);
        }
        __syncthreads();
#ifdef HAS_MX
        int8v a[4], b[4];
        #pragma unroll
        for (int f = 0; f < 4; ++f) {
            a[f] = load_frag(As, wm + f * 16 + r, g, 0);
            b[f] = load_frag(Bs, wn + f * 16 + r, g, 0);
        }
        #pragma unroll
        for (int fr = 0; fr < 4; ++fr)
            #pragma unroll
            for (int fc = 0; fc < 4; ++fc)
                acc[fr][fc] = __builtin_amdgcn_mfma_scale_f32_16x16x128_f8f6f4(
                    a[fr], b[fc], acc[fr][fc], 0, 0, 0, 0x7F7F7F7F, 0, 0x7F7F7F7F);
#else
        #pragma unroll
        for (int ks = 0; ks < 4; ++ks) {
            long long a8[4], b8[4];
            #pragma unroll
            for (int f = 0; f < 4; ++f) {
                a8[f] = load_frag8(As, wm + f * 16 + r, 4 * ks + g, 0);
                b8[f] = load_frag8(Bs, wn + f * 16 + r, 4 * ks + g, 0);
            }
            #pragma unroll
            for (int fr = 0; fr < 4; ++fr)
                #pragma unroll
                for (int fc = 0; fc < 4; ++fc)
                    acc[fr][fc] = __builtin_amdgcn_mfma_f32_16x16x32_fp8_fp8(
                        a8[fr], b8[fc], acc[fr][fc], 0, 0, 0);
        }
#endif
        __syncthreads();
    }

    const int colr = r, quad = g;
    float wgv[4], b2v[4];
    #pragma unroll
    for (int fc = 0; fc < 4; ++fc) {
        int col = n0 + wn + fc * 16 + colr;
        wgv[fc] = Wg[n * DDIM + col];
        b2v[fc] = b2[n * DDIM + col];
    }
    float rowsum[4][4];
    #pragma unroll
    for (int fr = 0; fr < 4; ++fr)
        #pragma unroll
        for (int rg = 0; rg < 4; ++rg) {
            float s = 0.f;
            #pragma unroll
            for (int fc = 0; fc < 4; ++fc) {
                float x = fast_tanh(acc[fr][fc][rg] + b2v[fc]);
                s = fmaf(x, wgv[fc], s);
            }
            rowsum[fr][rg] = s;
        }
    #pragma unroll
    for (int sh = 1; sh < 16; sh <<= 1)
        #pragma unroll
        for (int fr = 0; fr < 4; ++fr)
            #pragma unroll
            for (int rg = 0; rg < 4; ++rg)
                rowsum[fr][rg] += __shfl_xor(rowsum[fr][rg], sh);
    if (colr == 0) {
        float* Ln = logits + (size_t)n * ROWS;
        #pragma unroll
        for (int fr = 0; fr < 4; ++fr) {
            int rowb = m0 + wm + fr * 16 + quad * 4;
            #pragma unroll
            for (int rg = 0; rg < 4; ++rg)
                atomicAdd(&Ln[rowb + rg], rowsum[fr][rg]);
        }
    }
}

// ---------- topcand: per (n,b) top-64 of 4096 (single kernel) ----------
__global__ __launch_bounds__(256)
void topcand_kernel(const float* __restrict__ logits, int* __restrict__ cand,
                    float* __restrict__ ex_logit) {
    __shared__ float lv[LSEQ];
    __shared__ float cv[256];
    __shared__ int   ci[256];
    int p = blockIdx.x, n = p >> 2, b = p & 3;
    int t = threadIdx.x, lane = t & 63, w = t >> 6;
    const float* L = logits + (size_t)n * ROWS + (size_t)b * LSEQ;
    for (int i = t; i < LSEQ; i += 256) lv[i] = L[i];
    __syncthreads();
    // phase 1: each wave extracts top-64 of its 1024 (register-resident)
    float mv[16];
    int base = w * 1024;
    #pragma unroll
    for (int j = 0; j < 16; ++j) mv[j] = lv[base + j * 64 + lane];
    for (int rd = 0; rd < 64; ++rd) {
        float best = mv[0]; int bj = 0;
        #pragma unroll
        for (int j = 1; j < 16; ++j)
            if (mv[j] > best) { best = mv[j]; bj = j; }
        int bidx = base + bj * 64 + lane;
        float rv = best; int ridx = bidx;
        #pragma unroll
        for (int s = 1; s < 64; s <<= 1) {
            float ov = __shfl_xor(rv, s); int oi = __shfl_xor(ridx, s);
            if (ov > rv || (ov == rv && oi < ridx)) { rv = ov; ridx = oi; }
        }
        if (lane == 0) { cv[w * 64 + rd] = rv; ci[w * 64 + rd] = ridx; }
        if (ridx == bidx) mv[bj] = -1e30f;
    }
    __syncthreads();
    // phase 2: wave 0 merges 256 -> top-64; wave 1 zeroes ex_logit
    if (w == 0) {
        float v4[4]; int i4[4];
        #pragma unroll
        for (int k = 0; k < 4; ++k) { v4[k] = cv[k * 64 + lane]; i4[k] = ci[k * 64 + lane]; }
        for (int rd = 0; rd < 64; ++rd) {
            float best = v4[0]; int bi = i4[0]; int bk = 0;
            #pragma unroll
            for (int k = 1; k < 4; ++k)
                if (v4[k] > best || (v4[k] == best && i4[k] < bi)) { best = v4[k]; bi = i4[k]; bk = k; }
            float rv = best; int ridx = bi;
            #pragma unroll
            for (int s = 1; s < 64; s <<= 1) {
                float ov = __shfl_xor(rv, s); int oi = __shfl_xor(ridx, s);
                if (ov > rv || (ov == rv && oi < ridx)) { rv = ov; ridx = oi; }
            }
            if (lane == 0) cand[p * NCAND + rd] = ridx;
            if (ridx == bi) v4[bk] = -1e30f;
        }
    } else if (w == 1) {
        ex_logit[p * NCAND + lane] = 0.f;
    }
}

// ---------- exact fp32 recompute: phase 1 (h) ----------
// grid 64p x 4ct x 8jc = 2048 blocks, 16 cands per block
__global__ __launch_bounds__(256)
void exact_h_kernel(const float* __restrict__ query,
                    const float* __restrict__ W1, const float* __restrict__ b1,
                    const int* __restrict__ cand, float* __restrict__ ex_h) {
    __shared__ float qs[DDIM][QPAD];
    __shared__ float hpart[4][16][64];
    int blk = blockIdx.x;
    int p = blk >> 5, r5 = blk & 31;
    int ct = r5 >> 3, jc = r5 & 7;
    int n = p >> 2, b = p & 3;
    int t = threadIdx.x, jj = t & 63, dg = t >> 6;
    int j = jc * 64 + jj;
    for (int c = 0; c < 16; ++c) {
        int li = cand[p * NCAND + ct * 16 + c];
        const float* qr = query + ((size_t)b * LSEQ + li) * DDIM;
        for (int d = t; d < DDIM; d += 256) qs[d][c] = qr[d];
    }
    __syncthreads();
    const float* W1n = W1 + (size_t)n * DDIM * DDIM;
    float acc[16] = {};
    for (int d = dg * 128; d < dg * 128 + 128; ++d) {
        float wvv = W1n[(size_t)d * DDIM + j];
        const float4* qv = (const float4*)&qs[d][0];
        #pragma unroll
        for (int c4 = 0; c4 < 4; ++c4) {
            float4 q4 = qv[c4];
            acc[c4 * 4 + 0] = fmaf(q4.x, wvv, acc[c4 * 4 + 0]);
            acc[c4 * 4 + 1] = fmaf(q4.y, wvv, acc[c4 * 4 + 1]);
            acc[c4 * 4 + 2] = fmaf(q4.z, wvv, acc[c4 * 4 + 2]);
            acc[c4 * 4 + 3] = fmaf(q4.w, wvv, acc[c4 * 4 + 3]);
        }
    }
    #pragma unroll
    for (int c = 0; c < 16; ++c) hpart[dg][c][jj] = acc[c];
    __syncthreads();
    const float slope = 0.01f + 0.0125f * n;
    float bias = b1[n * DDIM + j];
    for (int cc = dg; cc < 16; cc += 4) {
        float h = hpart[0][cc][jj] + hpart[1][cc][jj] + hpart[2][cc][jj]
                + hpart[3][cc][jj] + bias;
        h = h >= 0.f ? h : h * slope;
        ex_h[((size_t)p * NCAND + ct * 16 + cc) * DDIM + j] = h;
    }
}

// ---------- exact phase 2: x + exact logits ----------
__global__ __launch_bounds__(256)
void exact_x_kernel(const float* __restrict__ ex_h,
                    const float* __restrict__ W2, const float* __restrict__ b2,
                    const float* __restrict__ Wg,
                    float* __restrict__ ex_x, float* __restrict__ ex_logit) {
    __shared__ float hs[DDIM][QPAD];
    __shared__ float xpart[4][16][64];
    int blk = blockIdx.x;
    int p = blk >> 5, r5 = blk & 31;
    int ct = r5 >> 3, jc = r5 & 7;
    int n = p >> 2;
    int t = threadIdx.x, jj = t & 63, dg = t >> 6;
    int j = jc * 64 + jj;
    for (int c = 0; c < 16; ++c) {
        const float* hr = ex_h + ((size_t)p * NCAND + ct * 16 + c) * DDIM;
        for (int d = t; d < DDIM; d += 256) hs[d][c] = hr[d];
    }
    __syncthreads();
    const float* W2n = W2 + (size_t)n * DDIM * DDIM;
    float acc[16] = {};
    for (int d = dg * 128; d < dg * 128 + 128; ++d) {
        float wvv = W2n[(size_t)d * DDIM + j];
        const float4* hv = (const float4*)&hs[d][0];
        #pragma unroll
        for (int c4 = 0; c4 < 4; ++c4) {
            float4 h4 = hv[c4];
            acc[c4 * 4 + 0] = fmaf(h4.x, wvv, acc[c4 * 4 + 0]);
            acc[c4 * 4 + 1] = fmaf(h4.y, wvv, acc[c4 * 4 + 1]);
            acc[c4 * 4 + 2] = fmaf(h4.z, wvv, acc[c4 * 4 + 2]);
            acc[c4 * 4 + 3] = fmaf(h4.w, wvv, acc[c4 * 4 + 3]);
        }
    }
    #pragma unroll
    for (int c = 0; c < 16; ++c) xpart[dg][c][jj] = acc[c];
    __syncthreads();
    float bias = b2[n * DDIM + j];
    float wg = Wg[n * DDIM + j];
    for (int cc = dg; cc < 16; cc += 4) {
        float a = xpart[0][cc][jj] + xpart[1][cc][jj] + xpart[2][cc][jj]
                + xpart[3][cc][jj] + bias;
        float x = tanhf(a);
        ex_x[((size_t)p * NCAND + ct * 16 + cc) * DDIM + j] = x;
        float lp = x * wg;
        #pragma unroll
        for (int s = 1; s < 64; s <<= 1) lp += __shfl_xor(lp, s);
        if (jj == 0) atomicAdd(&ex_logit[p * NCAND + ct * 16 + cc], lp);
    }
}

// ---------- final: exact top-8 of 64, weight, combine, normalize ----------
__global__ __launch_bounds__(64)
void final_kernel(const float* __restrict__ ex_x, const float* __restrict__ ex_logit,
                  const int* __restrict__ cand, float* __restrict__ out)
{
    __shared__ float w8s[KTOP];
    __shared__ int   s8s[KTOP];
    int p = blockIdx.x, n = p >> 2, b = p & 3;
    int t = threadIdx.x;
    float myv = ex_logit[p * NCAND + t];
    int myidx = cand[p * NCAND + t];
    float lmax = 0.f;
    for (int k = 0; k < KTOP; ++k) {
        float rv = myv; int ridx = myidx; int rl = t;
        #pragma unroll
        for (int s = 1; s < 64; s <<= 1) {
            float ov = __shfl_xor(rv, s); int oi = __shfl_xor(ridx, s); int ol = __shfl_xor(rl, s);
            if (ov > rv || (ov == rv && oi < ridx)) { rv = ov; ridx = oi; rl = ol; }
        }
        if (k == 0) lmax = rv;
        if (t == 0) { w8s[k] = __expf(rv - lmax); s8s[k] = rl; }
        if (t == rl) myv = -1e30f;
    }
    __syncthreads();
    float cvv[8];
    float sq = 0.f;
    int idx = 0;
    for (int d = t; d < DDIM; d += 64, ++idx) {
        float s = 0.f;
        #pragma unroll
        for (int k = 0; k < KTOP; ++k)
            s = fmaf(w8s[k], ex_x[((size_t)p * NCAND + s8s[k]) * DDIM + d], s);
        cvv[idx] = s;
        sq += s * s;
    }
    #pragma unroll
    for (int s = 1; s < 64; s <<= 1) sq += __shfl_xor(sq, s);
    float norm = fmaxf(sqrtf(sq), 1e-12f);
    idx = 0;
    for (int d = t; d < DDIM; d += 64, ++idx)
        out[((size_t)b * NMEM + n) * DDIM + d] = cvv[idx] / norm;
}

extern "C" void kernel_launch(void* const* d_in, const int* in_sizes, int n_in,
                              void* d_out, int out_size, void* d_ws, size_t ws_size,
                              hipStream_t stream)
{
    const float* query = (const float*)d_in[0];
    const float* W1    = (const float*)d_in[1];
    const float* b1    = (const float*)d_in[2];
    const float* W2    = (const float*)d_in[3];
    const float* b2    = (const float*)d_in[4];
    const float* Wg    = (const float*)d_in[5];
    // d_in[6] = bg cancels under softmax+normalize; d_in[7] = topk (hardcoded 8)

    char* ws = (char*)d_ws;
    const size_t MB = 1024 * 1024;
    unsigned char* Q8   = (unsigned char*)(ws);                  // 8 MB
    unsigned char* W1T8 = (unsigned char*)(ws + 8 * MB);         // 4 MB
    unsigned char* W2T8 = (unsigned char*)(ws + 12 * MB);        // 4 MB
    float* logits   = (float*)(ws + 16 * MB);                    // 1 MB
    int*   cand     = (int*)  (ws + 17 * MB);                    // 16 KB
    float* ex_logit = (float*)(ws + 17 * MB + 16384);            // 16 KB
    float* ex_h     = (float*)(ws + 20 * MB);                    // 8 MB
    float* ex_x     = (float*)(ws + 28 * MB);                    // 8 MB
    unsigned char* H = (unsigned char*)(ws + 40 * MB);           // g x 8 MB

    int g = 1;
    if      (ws_size >= 40 * MB + 128 * MB) g = 16;
    else if (ws_size >= 40 * MB +  64 * MB) g = 8;
    else if (ws_size >= 40 * MB +  32 * MB) g = 4;
    else if (ws_size >= 40 * MB +  16 * MB) g = 2;

    prep_kernel<<<4352, 256, 0, stream>>>(query, W1, W2, Q8, W1T8, W2T8, logits);

    for (int s0 = 0; s0 < NMEM; s0 += g) {
        gemm1_kernel<<<dim3(4, 128, g), 256, 0, stream>>>(Q8, W1T8, b1, H, s0);
        gemm2_kernel<<<dim3(4, 128, g), 256, 0, stream>>>(H, W2T8, b2, Wg, logits, s0);
    }

    topcand_kernel<<<64, 256, 0, stream>>>(logits, cand, ex_logit);
    exact_h_kernel<<<2048, 256, 0, stream>>>(query, W1, b1, cand, ex_h);
    exact_x_kernel<<<2048, 256, 0, stream>>>(ex_h, W2, b2, Wg, ex_x, ex_logit);
    final_kernel<<<64, 64, 0, stream>>>(ex_x, ex_logit, cand, (float*)d_out);
}

// Round 5
// 627.037 us; speedup vs baseline: 1.4017x; 1.0629x over previous
//
#include <hip/hip_runtime.h>
#include <hip/hip_bf16.h>
#include <cstdint>
#include <cstddef>

// Problem constants
#define NMEM 16
#define DDIM 512
#define BATCH 4
#define LSEQ 4096
#define ROWS 16384      // BATCH*LSEQ
#define NCAND 64        // fp8-noise safety: rank-8..64 gap ~4.6 sigma
#define KTOP 8
#define QPAD 20

typedef __attribute__((ext_vector_type(4))) float f32x4;
typedef __attribute__((ext_vector_type(8))) int int8v;

__device__ inline void gld16(const void* gptr, void* lptr) {
    __builtin_amdgcn_global_load_lds(
        (const __attribute__((address_space(1))) unsigned int*)gptr,
        (__attribute__((address_space(3))) unsigned int*)lptr,
        16, 0, 0);
}

__device__ inline float fast_tanh(float p) {
    p = fminf(fmaxf(p, -15.f), 15.f);
    float e = __expf(2.f * p);
    return (e - 1.f) / (e + 1.f);
}

// MX frag from a 128-B-row tile: lane holds k = g*32 + [0,32) as 2 swizzled b128 chunks
__device__ inline int8v load_frag(const unsigned char* Ts, int row, int g, int hs) {
    int h = (row >> hs) & 7;
    const int4* p0 = (const int4*)(Ts + row * 128 + (((2 * g) ^ h) << 4));
    const int4* p1 = (const int4*)(Ts + row * 128 + (((2 * g + 1) ^ h) << 4));
    int4 x = *p0, y = *p1;
    int8v v;
    v[0] = x.x; v[1] = x.y; v[2] = x.z; v[3] = x.w;
    v[4] = y.x; v[5] = y.y; v[6] = y.z; v[7] = y.w;
    return v;
}

// MX frag from the 512-B-row h buffer: k = kt4*128 + g*32 + [0,32)
__device__ inline int8v load_frag_h(const unsigned char* hbuf, int row, int kt4, int g) {
    int hq = row & 7;
    int C0 = kt4 * 8 + 2 * g;
    const int4* p0 = (const int4*)(hbuf + row * 512 + ((C0 ^ hq) << 4));
    const int4* p1 = (const int4*)(hbuf + row * 512 + (((C0 + 1) ^ hq) << 4));
    int4 x = *p0, y = *p1;
    int8v v;
    v[0] = x.x; v[1] = x.y; v[2] = x.z; v[3] = x.w;
    v[4] = y.x; v[5] = y.y; v[6] = y.z; v[7] = y.w;
    return v;
}

// ---------- fused prep: Q->fp8, W1/W2 transpose->fp8, zero logits ----------
// grid: 2048 (Q) + 1024 (W1) + 1024 (W2) + 256 (logits zero) = 4352
__global__ __launch_bounds__(256)
void prep_kernel(const float* __restrict__ query,
                 const float* __restrict__ W1, const float* __restrict__ W2,
                 unsigned char* __restrict__ Q8,
                 unsigned char* __restrict__ W1T8, unsigned char* __restrict__ W2T8,
                 float* __restrict__ logits) {
    int blk = blockIdx.x, t = threadIdx.x;
    if (blk < 2048) {                       // Q convert: 16 els/thread
        size_t base = ((size_t)blk * 256 + t) * 16;
        const float4* in = (const float4*)(query + base);
        int4 o; int* op = (int*)&o;
        #pragma unroll
        for (int q = 0; q < 4; ++q) {
            float4 v = in[q];
            int lo = __builtin_amdgcn_cvt_pk_fp8_f32(v.x, v.y, 0, false);
            op[q] = __builtin_amdgcn_cvt_pk_fp8_f32(v.z, v.w, lo, true);
        }
        *(int4*)(Q8 + base) = o;
    } else if (blk < 4096) {                // W transpose+convert, 64x64 tiles
        __shared__ float tile[64][69];
        int bid = blk - 2048;               // 0..2047: 1024 per matrix
        const float* Win = W1; unsigned char* Wout = W1T8;
        if (bid >= 1024) { bid -= 1024; Win = W2; Wout = W2T8; }
        int n = bid >> 6, t64 = bid & 63;   // n in [0,16), 64 tiles of 64x64
        int dt = (t64 >> 3) << 6, jt = (t64 & 7) << 6;
        const float* inN = Win + (size_t)n * DDIM * DDIM;
        unsigned char* outN = Wout + (size_t)n * DDIM * DDIM;
        int rr = t >> 4, cc = (t & 15) * 4;
        #pragma unroll
        for (int pass = 0; pass < 4; ++pass) {
            int row = rr + pass * 16;
            float4 v = *(const float4*)(inN + (size_t)(dt + row) * DDIM + jt + cc);
            tile[row][cc] = v.x; tile[row][cc + 1] = v.y;
            tile[row][cc + 2] = v.z; tile[row][cc + 3] = v.w;
        }
        __syncthreads();
        #pragma unroll
        for (int pass = 0; pass < 4; ++pass) {
            int jl = rr + pass * 16;
            float f0 = tile[cc][jl], f1 = tile[cc + 1][jl];
            float f2 = tile[cc + 2][jl], f3 = tile[cc + 3][jl];
            int lo = __builtin_amdgcn_cvt_pk_fp8_f32(f0, f1, 0, false);
            int dw = __builtin_amdgcn_cvt_pk_fp8_f32(f2, f3, lo, true);
            *(int*)(outN + (size_t)(jt + jl) * DDIM + dt + cc) = dw;
        }
    } else {                                // zero logits (1 MB)
        int bid = blk - 4096;               // 0..255
        ((int4*)logits)[bid * 256 + t] = int4{0, 0, 0, 0};
    }
}

// ---------- fused MLP: logits[n, rows] += tanh(leaky(Q W1 + b1) W2 + b2) . Wg ----------
// grid 4096 = 256 m-tiles x 16 slots (n = id & 15 -> slot pinned to XCD n%8)
// block 256 = 4 waves in 2x2 grid; wave-tile 32 rows x 64 cols; h (64x512 fp8) LDS-resident
__global__ __launch_bounds__(256, 2)
void fused_mlp_kernel(const unsigned char* __restrict__ Q8,
                      const unsigned char* __restrict__ W1T8,
                      const unsigned char* __restrict__ W2T8,
                      const float* __restrict__ b1, const float* __restrict__ b2,
                      const float* __restrict__ Wg,
                      float* __restrict__ logits)
{
    __shared__ unsigned char hbuf[64 * 512];   // 32 KB
    __shared__ unsigned char As[64 * 128];     // 8 KB
    __shared__ unsigned char Bs[128 * 128];    // 16 KB
    const int id = blockIdx.x;
    const int n = id & 15;
    const int m0 = (id >> 4) * 64;
    const int tid = threadIdx.x, lane = tid & 63, w = tid >> 6;
    const int wm = (w >> 1) * 32, wn = (w & 1) * 64;
    const int r = lane & 15, g = lane >> 4;
    const unsigned char* Ag = Q8 + (size_t)m0 * DDIM;
    const unsigned char* W1n = W1T8 + (size_t)n * DDIM * DDIM;
    const unsigned char* W2n = W2T8 + (size_t)n * DDIM * DDIM;
    const float slope = 0.01f + 0.0125f * n;

    // ---- Phase A: h = leaky(Q W1 + b1) -> LDS (fp8, swizzled) ----
    for (int n0 = 0; n0 < 4; ++n0) {
        f32x4 acc[2][4] = {};
        const unsigned char* Bg = W1n + (size_t)(n0 * 128) * DDIM;
        for (int kt4 = 0; kt4 < 4; ++kt4) {
            int kt = kt4 * 128;
            #pragma unroll
            for (int i = 0; i < 2; ++i) {
                int c = i * 256 + tid;             // [0,512): 64 rows x 8 chunks
                int row = c >> 3, ch = c & 7;
                gld16(Ag + (size_t)row * DDIM + kt + ((ch ^ (row & 7)) << 4), &As[c * 16]);
            }
            #pragma unroll
            for (int i = 0; i < 4; ++i) {
                int c = i * 256 + tid;             // [0,1024): 128 rows x 8 chunks
                int row = c >> 3, ch = c & 7;
                gld16(Bg + (size_t)row * DDIM + kt + ((ch ^ ((row >> 2) & 7)) << 4), &Bs[c * 16]);
            }
            __syncthreads();
            int8v a[2], b[4];
            a[0] = load_frag(As, wm + r, g, 0);
            a[1] = load_frag(As, wm + 16 + r, g, 0);
            #pragma unroll
            for (int f = 0; f < 4; ++f)
                b[f] = load_frag(Bs, wn + r * 4 + f, g, 2);
            #pragma unroll
            for (int fr = 0; fr < 2; ++fr)
                #pragma unroll
                for (int fc = 0; fc < 4; ++fc)
                    acc[fr][fc] = __builtin_amdgcn_mfma_scale_f32_16x16x128_f8f6f4(
                        a[fr], b[fc], acc[fr][fc], 0, 0, 0, 0x7F7F7F7F, 0, 0x7F7F7F7F);
            __syncthreads();
        }
        // epilogue: bias + leaky, pack fp8, write into swizzled h
        const float4 b4 = *(const float4*)&b1[n * DDIM + n0 * 128 + wn + r * 4];
        const int C = n0 * 8 + (wn >> 4) + (r >> 2);
        #pragma unroll
        for (int fr = 0; fr < 2; ++fr) {
            #pragma unroll
            for (int rg = 0; rg < 4; ++rg) {
                int rr = wm + fr * 16 + g * 4 + rg;
                float v0 = acc[fr][0][rg] + b4.x; v0 = v0 >= 0.f ? v0 : v0 * slope;
                float v1 = acc[fr][1][rg] + b4.y; v1 = v1 >= 0.f ? v1 : v1 * slope;
                float v2 = acc[fr][2][rg] + b4.z; v2 = v2 >= 0.f ? v2 : v2 * slope;
                float v3 = acc[fr][3][rg] + b4.w; v3 = v3 >= 0.f ? v3 : v3 * slope;
                int lo = __builtin_amdgcn_cvt_pk_fp8_f32(v0, v1, 0, false);
                int dw = __builtin_amdgcn_cvt_pk_fp8_f32(v2, v3, lo, true);
                *(int*)&hbuf[rr * 512 + ((C ^ (rr & 7)) << 4) + ((r & 3) << 2)] = dw;
            }
        }
        __syncthreads();   // h chunk written before next n0 re-stages As/Bs
    }

    // ---- Phase B: rowsum_n(row) = sum_col tanh(h W2 + b2) * Wg ----
    float rowacc[2][4] = {};
    for (int c0 = 0; c0 < 4; ++c0) {
        f32x4 acc[2][4] = {};
        const unsigned char* Bg = W2n + (size_t)(c0 * 128) * DDIM;
        for (int kt4 = 0; kt4 < 4; ++kt4) {
            int kt = kt4 * 128;
            #pragma unroll
            for (int i = 0; i < 4; ++i) {
                int c = i * 256 + tid;
                int row = c >> 3, ch = c & 7;
                gld16(Bg + (size_t)row * DDIM + kt + ((ch ^ ((row >> 2) & 7)) << 4), &Bs[c * 16]);
            }
            __syncthreads();
            int8v a[2], b[4];
            a[0] = load_frag_h(hbuf, wm + r, kt4, g);
            a[1] = load_frag_h(hbuf, wm + 16 + r, kt4, g);
            #pragma unroll
            for (int f = 0; f < 4; ++f)
                b[f] = load_frag(Bs, wn + r * 4 + f, g, 2);
            #pragma unroll
            for (int fr = 0; fr < 2; ++fr)
                #pragma unroll
                for (int fc = 0; fc < 4; ++fc)
                    acc[fr][fc] = __builtin_amdgcn_mfma_scale_f32_16x16x128_f8f6f4(
                        a[fr], b[fc], acc[fr][fc], 0, 0, 0, 0x7F7F7F7F, 0, 0x7F7F7F7F);
            __syncthreads();
        }
        const float4 b24 = *(const float4*)&b2[n * DDIM + c0 * 128 + wn + r * 4];
        const float4 wg4 = *(const float4*)&Wg[n * DDIM + c0 * 128 + wn + r * 4];
        #pragma unroll
        for (int fr = 0; fr < 2; ++fr)
            #pragma unroll
            for (int rg = 0; rg < 4; ++rg) {
                float s = 0.f;
                s = fmaf(fast_tanh(acc[fr][0][rg] + b24.x), wg4.x, s);
                s = fmaf(fast_tanh(acc[fr][1][rg] + b24.y), wg4.y, s);
                s = fmaf(fast_tanh(acc[fr][2][rg] + b24.z), wg4.z, s);
                s = fmaf(fast_tanh(acc[fr][3][rg] + b24.w), wg4.w, s);
                rowacc[fr][rg] += s;
            }
    }
    // reduce over the 16 col-lanes (r), then atomic into logits
    #pragma unroll
    for (int sh = 1; sh < 16; sh <<= 1)
        #pragma unroll
        for (int fr = 0; fr < 2; ++fr)
            #pragma unroll
            for (int rg = 0; rg < 4; ++rg)
                rowacc[fr][rg] += __shfl_xor(rowacc[fr][rg], sh);
    if (r == 0) {
        float* Ln = logits + (size_t)n * ROWS + m0;
        #pragma unroll
        for (int fr = 0; fr < 2; ++fr) {
            int rowb = wm + fr * 16 + g * 4;
            #pragma unroll
            for (int rg = 0; rg < 4; ++rg)
                atomicAdd(&Ln[rowb + rg], rowacc[fr][rg]);
        }
    }
}

// ---------- topcand: per (n,b) top-64 of 4096 (single kernel) ----------
__global__ __launch_bounds__(256)
void topcand_kernel(const float* __restrict__ logits, int* __restrict__ cand,
                    float* __restrict__ ex_logit) {
    __shared__ float lv[LSEQ];
    __shared__ float cv[256];
    __shared__ int   ci[256];
    int p = blockIdx.x, n = p >> 2, b = p & 3;
    int t = threadIdx.x, lane = t & 63, w = t >> 6;
    const float* L = logits + (size_t)n * ROWS + (size_t)b * LSEQ;
    for (int i = t; i < LSEQ; i += 256) lv[i] = L[i];
    __syncthreads();
    // phase 1: each wave extracts top-64 of its 1024 (register-resident)
    float mv[16];
    int base = w * 1024;
    #pragma unroll
    for (int j = 0; j < 16; ++j) mv[j] = lv[base + j * 64 + lane];
    for (int rd = 0; rd < 64; ++rd) {
        float best = mv[0]; int bj = 0;
        #pragma unroll
        for (int j = 1; j < 16; ++j)
            if (mv[j] > best) { best = mv[j]; bj = j; }
        int bidx = base + bj * 64 + lane;
        float rv = best; int ridx = bidx;
        #pragma unroll
        for (int s = 1; s < 64; s <<= 1) {
            float ov = __shfl_xor(rv, s); int oi = __shfl_xor(ridx, s);
            if (ov > rv || (ov == rv && oi < ridx)) { rv = ov; ridx = oi; }
        }
        if (lane == 0) { cv[w * 64 + rd] = rv; ci[w * 64 + rd] = ridx; }
        if (ridx == bidx) mv[bj] = -1e30f;
    }
    __syncthreads();
    // phase 2: wave 0 merges 256 -> top-64; wave 1 zeroes ex_logit
    if (w == 0) {
        float v4[4]; int i4[4];
        #pragma unroll
        for (int k = 0; k < 4; ++k) { v4[k] = cv[k * 64 + lane]; i4[k] = ci[k * 64 + lane]; }
        for (int rd = 0; rd < 64; ++rd) {
            float best = v4[0]; int bi = i4[0]; int bk = 0;
            #pragma unroll
            for (int k = 1; k < 4; ++k)
                if (v4[k] > best || (v4[k] == best && i4[k] < bi)) { best = v4[k]; bi = i4[k]; bk = k; }
            float rv = best; int ridx = bi;
            #pragma unroll
            for (int s = 1; s < 64; s <<= 1) {
                float ov = __shfl_xor(rv, s); int oi = __shfl_xor(ridx, s);
                if (ov > rv || (ov == rv && oi < ridx)) { rv = ov; ridx = oi; }
            }
            if (lane == 0) cand[p * NCAND + rd] = ridx;
            if (ridx == bi) v4[bk] = -1e30f;
        }
    } else if (w == 1) {
        ex_logit[p * NCAND + lane] = 0.f;
    }
}

// ---------- exact fp32 recompute: phase 1 (h) ----------
// grid 64p x 4ct x 8jc = 2048 blocks, 16 cands per block
__global__ __launch_bounds__(256)
void exact_h_kernel(const float* __restrict__ query,
                    const float* __restrict__ W1, const float* __restrict__ b1,
                    const int* __restrict__ cand, float* __restrict__ ex_h) {
    __shared__ float qs[DDIM][QPAD];
    __shared__ float hpart[4][16][64];
    int blk = blockIdx.x;
    int p = blk >> 5, r5 = blk & 31;
    int ct = r5 >> 3, jc = r5 & 7;
    int n = p >> 2, b = p & 3;
    int t = threadIdx.x, jj = t & 63, dg = t >> 6;
    int j = jc * 64 + jj;
    for (int c = 0; c < 16; ++c) {
        int li = cand[p * NCAND + ct * 16 + c];
        const float* qr = query + ((size_t)b * LSEQ + li) * DDIM;
        for (int d = t; d < DDIM; d += 256) qs[d][c] = qr[d];
    }
    __syncthreads();
    const float* W1n = W1 + (size_t)n * DDIM * DDIM;
    float acc[16] = {};
    for (int d = dg * 128; d < dg * 128 + 128; ++d) {
        float wvv = W1n[(size_t)d * DDIM + j];
        const float4* qv = (const float4*)&qs[d][0];
        #pragma unroll
        for (int c4 = 0; c4 < 4; ++c4) {
            float4 q4 = qv[c4];
            acc[c4 * 4 + 0] = fmaf(q4.x, wvv, acc[c4 * 4 + 0]);
            acc[c4 * 4 + 1] = fmaf(q4.y, wvv, acc[c4 * 4 + 1]);
            acc[c4 * 4 + 2] = fmaf(q4.z, wvv, acc[c4 * 4 + 2]);
            acc[c4 * 4 + 3] = fmaf(q4.w, wvv, acc[c4 * 4 + 3]);
        }
    }
    #pragma unroll
    for (int c = 0; c < 16; ++c) hpart[dg][c][jj] = acc[c];
    __syncthreads();
    const float slope = 0.01f + 0.0125f * n;
    float bias = b1[n * DDIM + j];
    for (int cc = dg; cc < 16; cc += 4) {
        float h = hpart[0][cc][jj] + hpart[1][cc][jj] + hpart[2][cc][jj]
                + hpart[3][cc][jj] + bias;
        h = h >= 0.f ? h : h * slope;
        ex_h[((size_t)p * NCAND + ct * 16 + cc) * DDIM + j] = h;
    }
}

// ---------- exact phase 2: x + exact logits ----------
__global__ __launch_bounds__(256)
void exact_x_kernel(const float* __restrict__ ex_h,
                    const float* __restrict__ W2, const float* __restrict__ b2,
                    const float* __restrict__ Wg,
                    float* __restrict__ ex_x, float* __restrict__ ex_logit) {
    __shared__ float hs[DDIM][QPAD];
    __shared__ float xpart[4][16][64];
    int blk = blockIdx.x;
    int p = blk >> 5, r5 = blk & 31;
    int ct = r5 >> 3, jc = r5 & 7;
    int n = p >> 2;
    int t = threadIdx.x, jj = t & 63, dg = t >> 6;
    int j = jc * 64 + jj;
    for (int c = 0; c < 16; ++c) {
        const float* hr = ex_h + ((size_t)p * NCAND + ct * 16 + c) * DDIM;
        for (int d = t; d < DDIM; d += 256) hs[d][c] = hr[d];
    }
    __syncthreads();
    const float* W2n = W2 + (size_t)n * DDIM * DDIM;
    float acc[16] = {};
    for (int d = dg * 128; d < dg * 128 + 128; ++d) {
        float wvv = W2n[(size_t)d * DDIM + j];
        const float4* hv = (const float4*)&hs[d][0];
        #pragma unroll
        for (int c4 = 0; c4 < 4; ++c4) {
            float4 h4 = hv[c4];
            acc[c4 * 4 + 0] = fmaf(h4.x, wvv, acc[c4 * 4 + 0]);
            acc[c4 * 4 + 1] = fmaf(h4.y, wvv, acc[c4 * 4 + 1]);
            acc[c4 * 4 + 2] = fmaf(h4.z, wvv, acc[c4 * 4 + 2]);
            acc[c4 * 4 + 3] = fmaf(h4.w, wvv, acc[c4 * 4 + 3]);
        }
    }
    #pragma unroll
    for (int c = 0; c < 16; ++c) xpart[dg][c][jj] = acc[c];
    __syncthreads();
    float bias = b2[n * DDIM + j];
    float wg = Wg[n * DDIM + j];
    for (int cc = dg; cc < 16; cc += 4) {
        float a = xpart[0][cc][jj] + xpart[1][cc][jj] + xpart[2][cc][jj]
                + xpart[3][cc][jj] + bias;
        float x = tanhf(a);
        ex_x[((size_t)p * NCAND + ct * 16 + cc) * DDIM + j] = x;
        float lp = x * wg;
        #pragma unroll
        for (int s = 1; s < 64; s <<= 1) lp += __shfl_xor(lp, s);
        if (jj == 0) atomicAdd(&ex_logit[p * NCAND + ct * 16 + cc], lp);
    }
}

// ---------- final: exact top-8 of 64, weight, combine, normalize ----------
__global__ __launch_bounds__(64)
void final_kernel(const float* __restrict__ ex_x, const float* __restrict__ ex_logit,
                  const int* __restrict__ cand, float* __restrict__ out)
{
    __shared__ float w8s[KTOP];
    __shared__ int   s8s[KTOP];
    int p = blockIdx.x, n = p >> 2, b = p & 3;
    int t = threadIdx.x;
    float myv = ex_logit[p * NCAND + t];
    int myidx = cand[p * NCAND + t];
    float lmax = 0.f;
    for (int k = 0; k < KTOP; ++k) {
        float rv = myv; int ridx = myidx; int rl = t;
        #pragma unroll
        for (int s = 1; s < 64; s <<= 1) {
            float ov = __shfl_xor(rv, s); int oi = __shfl_xor(ridx, s); int ol = __shfl_xor(rl, s);
            if (ov > rv || (ov == rv && oi < ridx)) { rv = ov; ridx = oi; rl = ol; }
        }
        if (k == 0) lmax = rv;
        if (t == 0) { w8s[k] = __expf(rv - lmax); s8s[k] = rl; }
        if (t == rl) myv = -1e30f;
    }
    __syncthreads();
    float cvv[8];
    float sq = 0.f;
    int idx = 0;
    for (int d = t; d < DDIM; d += 64, ++idx) {
        float s = 0.f;
        #pragma unroll
        for (int k = 0; k < KTOP; ++k)
            s = fmaf(w8s[k], ex_x[((size_t)p * NCAND + s8s[k]) * DDIM + d], s);
        cvv[idx] = s;
        sq += s * s;
    }
    #pragma unroll
    for (int s = 1; s < 64; s <<= 1) sq += __shfl_xor(sq, s);
    float norm = fmaxf(sqrtf(sq), 1e-12f);
    idx = 0;
    for (int d = t; d < DDIM; d += 64, ++idx)
        out[((size_t)b * NMEM + n) * DDIM + d] = cvv[idx] / norm;
}

extern "C" void kernel_launch(void* const* d_in, const int* in_sizes, int n_in,
                              void* d_out, int out_size, void* d_ws, size_t ws_size,
                              hipStream_t stream)
{
    const float* query = (const float*)d_in[0];
    const float* W1    = (const float*)d_in[1];
    const float* b1    = (const float*)d_in[2];
    const float* W2    = (const float*)d_in[3];
    const float* b2    = (const float*)d_in[4];
    const float* Wg    = (const float*)d_in[5];
    // d_in[6] = bg cancels under softmax+normalize; d_in[7] = topk (hardcoded 8)

    char* ws = (char*)d_ws;
    const size_t MB = 1024 * 1024;
    unsigned char* Q8   = (unsigned char*)(ws);                  // 8 MB
    unsigned char* W1T8 = (unsigned char*)(ws + 8 * MB);         // 4 MB
    unsigned char* W2T8 = (unsigned char*)(ws + 12 * MB);        // 4 MB
    float* logits   = (float*)(ws + 16 * MB);                    // 1 MB
    int*   cand     = (int*)  (ws + 17 * MB);                    // 16 KB
    float* ex_logit = (float*)(ws + 17 * MB + 16384);            // 16 KB
    float* ex_h     = (float*)(ws + 20 * MB);                    // 8 MB
    float* ex_x     = (float*)(ws + 28 * MB);                    // 8 MB

    prep_kernel<<<4352, 256, 0, stream>>>(query, W1, W2, Q8, W1T8, W2T8, logits);
    fused_mlp_kernel<<<4096, 256, 0, stream>>>(Q8, W1T8, W2T8, b1, b2, Wg, logits);
    topcand_kernel<<<64, 256, 0, stream>>>(logits, cand, ex_logit);
    exact_h_kernel<<<2048, 256, 0, stream>>>(query, W1, b1, cand, ex_h);
    exact_x_kernel<<<2048, 256, 0, stream>>>(ex_h, W2, b2, Wg, ex_x, ex_logit);
    final_kernel<<<64, 64, 0, stream>>>(ex_x, ex_logit, cand, (float*)d_out);
}

// Round 6
// 619.641 us; speedup vs baseline: 1.4184x; 1.0119x over previous
//
#include <hip/hip_runtime.h>
#include <hip/hip_bf16.h>
#include <cstdint>
#include <cstddef>

// Problem constants
#define NMEM 16
#define DDIM 512
#define BATCH 4
#define LSEQ 4096
#define ROWS 16384      // BATCH*LSEQ
#define NCAND 64        // fp8-noise safety: rank-8..64 gap ~4.6 sigma
#define KTOP 8
#define QPAD 20

typedef __attribute__((ext_vector_type(4))) float f32x4;
typedef __attribute__((ext_vector_type(16))) float f32x16;
typedef __attribute__((ext_vector_type(8))) int int8v;

__device__ inline void gld16(const void* gptr, void* lptr) {
    __builtin_amdgcn_global_load_lds(
        (const __attribute__((address_space(1))) unsigned int*)gptr,
        (__attribute__((address_space(3))) unsigned int*)lptr,
        16, 0, 0);
}

__device__ inline float fast_tanh(float p) {
    p = fminf(fmaxf(p, -15.f), 15.f);
    float e = __expf(2.f * p);
    return (e - 1.f) / (e + 1.f);
}

// MX frag from a 128-B-row tile: chunks 2g^h, (2g+1)^h of row (h = swizzle key)
__device__ inline int8v load_frag(const unsigned char* Ts, int row, int g, int hs) {
    int h = (row >> hs) & 7;
    const int4* p0 = (const int4*)(Ts + row * 128 + (((2 * g) ^ h) << 4));
    const int4* p1 = (const int4*)(Ts + row * 128 + (((2 * g + 1) ^ h) << 4));
    int4 x = *p0, y = *p1;
    int8v v;
    v[0] = x.x; v[1] = x.y; v[2] = x.z; v[3] = x.w;
    v[4] = y.x; v[5] = y.y; v[6] = y.z; v[7] = y.w;
    return v;
}

// ---------- fused prep: Q->fp8, W1/W2 transpose->fp8, zero logits ----------
// grid: 2048 (Q) + 1024 (W1) + 1024 (W2) + 256 (logits zero) = 4352
__global__ __launch_bounds__(256)
void prep_kernel(const float* __restrict__ query,
                 const float* __restrict__ W1, const float* __restrict__ W2,
                 unsigned char* __restrict__ Q8,
                 unsigned char* __restrict__ W1T8, unsigned char* __restrict__ W2T8,
                 float* __restrict__ logits) {
    int blk = blockIdx.x, t = threadIdx.x;
    if (blk < 2048) {                       // Q convert: 16 els/thread
        size_t base = ((size_t)blk * 256 + t) * 16;
        const float4* in = (const float4*)(query + base);
        int4 o; int* op = (int*)&o;
        #pragma unroll
        for (int q = 0; q < 4; ++q) {
            float4 v = in[q];
            int lo = __builtin_amdgcn_cvt_pk_fp8_f32(v.x, v.y, 0, false);
            op[q] = __builtin_amdgcn_cvt_pk_fp8_f32(v.z, v.w, lo, true);
        }
        *(int4*)(Q8 + base) = o;
    } else if (blk < 4096) {                // W transpose+convert, 64x64 tiles
        __shared__ float tile[64][69];
        int bid = blk - 2048;               // 0..2047: 1024 per matrix
        const float* Win = W1; unsigned char* Wout = W1T8;
        if (bid >= 1024) { bid -= 1024; Win = W2; Wout = W2T8; }
        int n = bid >> 6, t64 = bid & 63;   // n in [0,16), 64 tiles of 64x64
        int dt = (t64 >> 3) << 6, jt = (t64 & 7) << 6;
        const float* inN = Win + (size_t)n * DDIM * DDIM;
        unsigned char* outN = Wout + (size_t)n * DDIM * DDIM;
        int rr = t >> 4, cc = (t & 15) * 4;
        #pragma unroll
        for (int pass = 0; pass < 4; ++pass) {
            int row = rr + pass * 16;
            float4 v = *(const float4*)(inN + (size_t)(dt + row) * DDIM + jt + cc);
            tile[row][cc] = v.x; tile[row][cc + 1] = v.y;
            tile[row][cc + 2] = v.z; tile[row][cc + 3] = v.w;
        }
        __syncthreads();
        #pragma unroll
        for (int pass = 0; pass < 4; ++pass) {
            int jl = rr + pass * 16;
            float f0 = tile[cc][jl], f1 = tile[cc + 1][jl];
            float f2 = tile[cc + 2][jl], f3 = tile[cc + 3][jl];
            int lo = __builtin_amdgcn_cvt_pk_fp8_f32(f0, f1, 0, false);
            int dw = __builtin_amdgcn_cvt_pk_fp8_f32(f2, f3, lo, true);
            *(int*)(outN + (size_t)(jt + jl) * DDIM + dt + cc) = dw;
        }
    } else {                                // zero logits (1 MB)
        int bid = blk - 4096;               // 0..255
        ((int4*)logits)[bid * 256 + t] = int4{0, 0, 0, 0};
    }
}

// ---------- fused MLP (v2): logits[n, rows] += tanh(leaky(Q W1 + b1) W2 + b2) . Wg ----
// grid 4096 = 256 m-tiles x 16 slots. Block 256 = 4 waves: wave (rh, ch) covers
// rows rh*32..+32 x cols ch*64..+64 of each 128-col chunk, 32x32x64 MX MFMA.
// A-operand: Q/hbuf direct (regs/LDS) - no As staging. LDS 48 KB -> 3 blocks/CU.
__global__ __launch_bounds__(256, 3)
void fused_mlp_kernel(const unsigned char* __restrict__ Q8,
                      const unsigned char* __restrict__ W1T8,
                      const unsigned char* __restrict__ W2T8,
                      const float* __restrict__ b1, const float* __restrict__ b2,
                      const float* __restrict__ Wg,
                      float* __restrict__ logits)
{
    __shared__ unsigned char hbuf[64 * 512];   // 32 KB fp8 h, chunk^row&7 swizzle
    __shared__ unsigned char Bs[128 * 128];    // 16 KB W-tile (col-major rows, 128-B K)
    const int id = blockIdx.x;
    const int n = id & 15;
    const int m0 = (id >> 4) * 64;
    const int tid = threadIdx.x, lane = tid & 63, w = tid >> 6;
    const int rh = w >> 1, ch = w & 1;
    const int l31 = lane & 31, kh = lane >> 5;
    const unsigned char* W1n = W1T8 + (size_t)n * DDIM * DDIM;
    const unsigned char* W2n = W2T8 + (size_t)n * DDIM * DDIM;
    const float slope = 0.01f + 0.0125f * n;
    const unsigned char* Aq = Q8 + (size_t)(m0 + rh * 32 + l31) * DDIM + kh * 32;

    // ---- Phase A: h = leaky(Q W1 + b1) -> hbuf ----
    for (int n0 = 0; n0 < 4; ++n0) {
        f32x16 acc[2] = {};
        const unsigned char* Bg = W1n + (size_t)(n0 * 128) * DDIM;
        for (int kt = 0; kt < 4; ++kt) {
            // A-frags (regs): ks=0 at +0, ks=1 at +64
            int4 a00 = *(const int4*)(Aq + kt * 128);
            int4 a01 = *(const int4*)(Aq + kt * 128 + 16);
            int4 a10 = *(const int4*)(Aq + kt * 128 + 64);
            int4 a11 = *(const int4*)(Aq + kt * 128 + 64 + 16);
            int8v av[2];
            av[0][0] = a00.x; av[0][1] = a00.y; av[0][2] = a00.z; av[0][3] = a00.w;
            av[0][4] = a01.x; av[0][5] = a01.y; av[0][6] = a01.z; av[0][7] = a01.w;
            av[1][0] = a10.x; av[1][1] = a10.y; av[1][2] = a10.z; av[1][3] = a10.w;
            av[1][4] = a11.x; av[1][5] = a11.y; av[1][6] = a11.z; av[1][7] = a11.w;
            #pragma unroll
            for (int i = 0; i < 4; ++i) {
                int c = i * 256 + tid;
                int row = c >> 3, chk = c & 7;
                gld16(Bg + (size_t)row * DDIM + kt * 128 + ((chk ^ (row & 7)) << 4),
                      &Bs[c * 16]);
            }
            __syncthreads();
            #pragma unroll
            for (int ks = 0; ks < 2; ++ks)
                #pragma unroll
                for (int fc = 0; fc < 2; ++fc) {
                    int8v bfr = load_frag(Bs, ch * 64 + fc * 32 + l31, ks * 2 + kh, 0);
                    acc[fc] = __builtin_amdgcn_mfma_scale_f32_32x32x64_f8f6f4(
                        av[ks], bfr, acc[fc], 0, 0, 0, 0x7F7F7F7F, 0, 0x7F7F7F7F);
                }
            __syncthreads();
        }
        #pragma unroll
        for (int fc = 0; fc < 2; ++fc) {
            int D = n0 * 128 + ch * 64 + fc * 32 + l31;
            float bias = b1[n * DDIM + D];
            int doff = ((D >> 4) << 4) ^ 0;  // chunk base (pre-swizzle), plus D&15
            #pragma unroll
            for (int reg = 0; reg < 16; ++reg) {
                int row = rh * 32 + (reg & 3) + 8 * (reg >> 2) + 4 * kh;
                float v = acc[fc][reg] + bias;
                v = v >= 0.f ? v : v * slope;
                int pk = __builtin_amdgcn_cvt_pk_fp8_f32(v, v, 0, false);
                hbuf[row * 512 + ((((D >> 4) ^ (row & 7))) << 4) + (D & 15)]
                    = (unsigned char)(pk & 0xff);
            }
            (void)doff;
        }
    }

    // ---- Phase B: rowsum = sum_j tanh(h W2 + b2)[row][j] * Wg[j] ----
    float rowacc[16] = {};
    const int hrow = rh * 32 + l31, hq = hrow & 7;
    for (int n0 = 0; n0 < 4; ++n0) {
        f32x16 acc[2] = {};
        const unsigned char* Bg = W2n + (size_t)(n0 * 128) * DDIM;
        for (int kt = 0; kt < 4; ++kt) {
            #pragma unroll
            for (int i = 0; i < 4; ++i) {
                int c = i * 256 + tid;
                int row = c >> 3, chk = c & 7;
                gld16(Bg + (size_t)row * DDIM + kt * 128 + ((chk ^ (row & 7)) << 4),
                      &Bs[c * 16]);
            }
            __syncthreads();
            #pragma unroll
            for (int ks = 0; ks < 2; ++ks) {
                int C0 = kt * 8 + ks * 4 + 2 * kh;
                const int4* p0 = (const int4*)(hbuf + hrow * 512 + ((C0 ^ hq) << 4));
                const int4* p1 = (const int4*)(hbuf + hrow * 512 + (((C0 + 1) ^ hq) << 4));
                int4 x = *p0, y = *p1;
                int8v av;
                av[0] = x.x; av[1] = x.y; av[2] = x.z; av[3] = x.w;
                av[4] = y.x; av[5] = y.y; av[6] = y.z; av[7] = y.w;
                #pragma unroll
                for (int fc = 0; fc < 2; ++fc) {
                    int8v bfr = load_frag(Bs, ch * 64 + fc * 32 + l31, ks * 2 + kh, 0);
                    acc[fc] = __builtin_amdgcn_mfma_scale_f32_32x32x64_f8f6f4(
                        av, bfr, acc[fc], 0, 0, 0, 0x7F7F7F7F, 0, 0x7F7F7F7F);
                }
            }
            __syncthreads();
        }
        #pragma unroll
        for (int fc = 0; fc < 2; ++fc) {
            int j = n0 * 128 + ch * 64 + fc * 32 + l31;
            float bias = b2[n * DDIM + j];
            float wgv = Wg[n * DDIM + j];
            #pragma unroll
            for (int reg = 0; reg < 16; ++reg)
                rowacc[reg] = fmaf(fast_tanh(acc[fc][reg] + bias), wgv, rowacc[reg]);
        }
    }
    #pragma unroll
    for (int sh = 1; sh < 32; sh <<= 1)
        #pragma unroll
        for (int reg = 0; reg < 16; ++reg)
            rowacc[reg] += __shfl_xor(rowacc[reg], sh);
    if (l31 == 0) {
        float* Ln = logits + (size_t)n * ROWS + m0 + rh * 32 + 4 * kh;
        #pragma unroll
        for (int reg = 0; reg < 16; ++reg)
            atomicAdd(&Ln[(reg & 3) + 8 * (reg >> 2)], rowacc[reg]);
    }
}

// ---------- topcand: per (n,b) top-64 of 4096 (single kernel) ----------
__global__ __launch_bounds__(256)
void topcand_kernel(const float* __restrict__ logits, int* __restrict__ cand,
                    float* __restrict__ ex_logit) {
    __shared__ float lv[LSEQ];
    __shared__ float cv[256];
    __shared__ int   ci[256];
    int p = blockIdx.x, n = p >> 2, b = p & 3;
    int t = threadIdx.x, lane = t & 63, w = t >> 6;
    const float* L = logits + (size_t)n * ROWS + (size_t)b * LSEQ;
    for (int i = t; i < LSEQ; i += 256) lv[i] = L[i];
    __syncthreads();
    float mv[16];
    int base = w * 1024;
    #pragma unroll
    for (int j = 0; j < 16; ++j) mv[j] = lv[base + j * 64 + lane];
    for (int rd = 0; rd < 64; ++rd) {
        float best = mv[0]; int bj = 0;
        #pragma unroll
        for (int j = 1; j < 16; ++j)
            if (mv[j] > best) { best = mv[j]; bj = j; }
        int bidx = base + bj * 64 + lane;
        float rv = best; int ridx = bidx;
        #pragma unroll
        for (int s = 1; s < 64; s <<= 1) {
            float ov = __shfl_xor(rv, s); int oi = __shfl_xor(ridx, s);
            if (ov > rv || (ov == rv && oi < ridx)) { rv = ov; ridx = oi; }
        }
        if (lane == 0) { cv[w * 64 + rd] = rv; ci[w * 64 + rd] = ridx; }
        if (ridx == bidx) mv[bj] = -1e30f;
    }
    __syncthreads();
    if (w == 0) {
        float v4[4]; int i4[4];
        #pragma unroll
        for (int k = 0; k < 4; ++k) { v4[k] = cv[k * 64 + lane]; i4[k] = ci[k * 64 + lane]; }
        for (int rd = 0; rd < 64; ++rd) {
            float best = v4[0]; int bi = i4[0]; int bk = 0;
            #pragma unroll
            for (int k = 1; k < 4; ++k)
                if (v4[k] > best || (v4[k] == best && i4[k] < bi)) { best = v4[k]; bi = i4[k]; bk = k; }
            float rv = best; int ridx = bi;
            #pragma unroll
            for (int s = 1; s < 64; s <<= 1) {
                float ov = __shfl_xor(rv, s); int oi = __shfl_xor(ridx, s);
                if (ov > rv || (ov == rv && oi < ridx)) { rv = ov; ridx = oi; }
            }
            if (lane == 0) cand[p * NCAND + rd] = ridx;
            if (ridx == bi) v4[bk] = -1e30f;
        }
    } else if (w == 1) {
        ex_logit[p * NCAND + lane] = 0.f;
    }
}

// ---------- exact fp32 recompute: phase 1 (h) ----------
__global__ __launch_bounds__(256)
void exact_h_kernel(const float* __restrict__ query,
                    const float* __restrict__ W1, const float* __restrict__ b1,
                    const int* __restrict__ cand, float* __restrict__ ex_h) {
    __shared__ float qs[DDIM][QPAD];
    __shared__ float hpart[4][16][64];
    int blk = blockIdx.x;
    int p = blk >> 5, r5 = blk & 31;
    int ct = r5 >> 3, jc = r5 & 7;
    int n = p >> 2, b = p & 3;
    int t = threadIdx.x, jj = t & 63, dg = t >> 6;
    int j = jc * 64 + jj;
    for (int c = 0; c < 16; ++c) {
        int li = cand[p * NCAND + ct * 16 + c];
        const float* qr = query + ((size_t)b * LSEQ + li) * DDIM;
        for (int d = t; d < DDIM; d += 256) qs[d][c] = qr[d];
    }
    __syncthreads();
    const float* W1n = W1 + (size_t)n * DDIM * DDIM;
    float acc[16] = {};
    for (int d = dg * 128; d < dg * 128 + 128; ++d) {
        float wvv = W1n[(size_t)d * DDIM + j];
        const float4* qv = (const float4*)&qs[d][0];
        #pragma unroll
        for (int c4 = 0; c4 < 4; ++c4) {
            float4 q4 = qv[c4];
            acc[c4 * 4 + 0] = fmaf(q4.x, wvv, acc[c4 * 4 + 0]);
            acc[c4 * 4 + 1] = fmaf(q4.y, wvv, acc[c4 * 4 + 1]);
            acc[c4 * 4 + 2] = fmaf(q4.z, wvv, acc[c4 * 4 + 2]);
            acc[c4 * 4 + 3] = fmaf(q4.w, wvv, acc[c4 * 4 + 3]);
        }
    }
    #pragma unroll
    for (int c = 0; c < 16; ++c) hpart[dg][c][jj] = acc[c];
    __syncthreads();
    const float slope = 0.01f + 0.0125f * n;
    float bias = b1[n * DDIM + j];
    for (int cc = dg; cc < 16; cc += 4) {
        float h = hpart[0][cc][jj] + hpart[1][cc][jj] + hpart[2][cc][jj]
                + hpart[3][cc][jj] + bias;
        h = h >= 0.f ? h : h * slope;
        ex_h[((size_t)p * NCAND + ct * 16 + cc) * DDIM + j] = h;
    }
}

// ---------- exact phase 2: x + exact logits ----------
__global__ __launch_bounds__(256)
void exact_x_kernel(const float* __restrict__ ex_h,
                    const float* __restrict__ W2, const float* __restrict__ b2,
                    const float* __restrict__ Wg,
                    float* __restrict__ ex_x, float* __restrict__ ex_logit) {
    __shared__ float hs[DDIM][QPAD];
    __shared__ float xpart[4][16][64];
    int blk = blockIdx.x;
    int p = blk >> 5, r5 = blk & 31;
    int ct = r5 >> 3, jc = r5 & 7;
    int n = p >> 2;
    int t = threadIdx.x, jj = t & 63, dg = t >> 6;
    int j = jc * 64 + jj;
    for (int c = 0; c < 16; ++c) {
        const float* hr = ex_h + ((size_t)p * NCAND + ct * 16 + c) * DDIM;
        for (int d = t; d < DDIM; d += 256) hs[d][c] = hr[d];
    }
    __syncthreads();
    const float* W2n = W2 + (size_t)n * DDIM * DDIM;
    float acc[16] = {};
    for (int d = dg * 128; d < dg * 128 + 128; ++d) {
        float wvv = W2n[(size_t)d * DDIM + j];
        const float4* hv = (const float4*)&hs[d][0];
        #pragma unroll
        for (int c4 = 0; c4 < 4; ++c4) {
            float4 h4 = hv[c4];
            acc[c4 * 4 + 0] = fmaf(h4.x, wvv, acc[c4 * 4 + 0]);
            acc[c4 * 4 + 1] = fmaf(h4.y, wvv, acc[c4 * 4 + 1]);
            acc[c4 * 4 + 2] = fmaf(h4.z, wvv, acc[c4 * 4 + 2]);
            acc[c4 * 4 + 3] = fmaf(h4.w, wvv, acc[c4 * 4 + 3]);
        }
    }
    #pragma unroll
    for (int c = 0; c < 16; ++c) xpart[dg][c][jj] = acc[c];
    __syncthreads();
    float bias = b2[n * DDIM + j];
    float wg = Wg[n * DDIM + j];
    for (int cc = dg; cc < 16; cc += 4) {
        float a = xpart[0][cc][jj] + xpart[1][cc][jj] + xpart[2][cc][jj]
                + xpart[3][cc][jj] + bias;
        float x = tanhf(a);
        ex_x[((size_t)p * NCAND + ct * 16 + cc) * DDIM + j] = x;
        float lp = x * wg;
        #pragma unroll
        for (int s = 1; s < 64; s <<= 1) lp += __shfl_xor(lp, s);
        if (jj == 0) atomicAdd(&ex_logit[p * NCAND + ct * 16 + cc], lp);
    }
}

// ---------- final: exact top-8 of 64, weight, combine, normalize ----------
__global__ __launch_bounds__(64)
void final_kernel(const float* __restrict__ ex_x, const float* __restrict__ ex_logit,
                  const int* __restrict__ cand, float* __restrict__ out)
{
    __shared__ float w8s[KTOP];
    __shared__ int   s8s[KTOP];
    int p = blockIdx.x, n = p >> 2, b = p & 3;
    int t = threadIdx.x;
    float myv = ex_logit[p * NCAND + t];
    int myidx = cand[p * NCAND + t];
    float lmax = 0.f;
    for (int k = 0; k < KTOP; ++k) {
        float rv = myv; int ridx = myidx; int rl = t;
        #pragma unroll
        for (int s = 1; s < 64; s <<= 1) {
            float ov = __shfl_xor(rv, s); int oi = __shfl_xor(ridx, s); int ol = __shfl_xor(rl, s);
            if (ov > rv || (ov == rv && oi < ridx)) { rv = ov; ridx = oi; rl = ol; }
        }
        if (k == 0) lmax = rv;
        if (t == 0) { w8s[k] = __expf(rv - lmax); s8s[k] = rl; }
        if (t == rl) myv = -1e30f;
    }
    __syncthreads();
    float cvv[8];
    float sq = 0.f;
    int idx = 0;
    for (int d = t; d < DDIM; d += 64, ++idx) {
        float s = 0.f;
        #pragma unroll
        for (int k = 0; k < KTOP; ++k)
            s = fmaf(w8s[k], ex_x[((size_t)p * NCAND + s8s[k]) * DDIM + d], s);
        cvv[idx] = s;
        sq += s * s;
    }
    #pragma unroll
    for (int s = 1; s < 64; s <<= 1) sq += __shfl_xor(sq, s);
    float norm = fmaxf(sqrtf(sq), 1e-12f);
    idx = 0;
    for (int d = t; d < DDIM; d += 64, ++idx)
        out[((size_t)b * NMEM + n) * DDIM + d] = cvv[idx] / norm;
}

extern "C" void kernel_launch(void* const* d_in, const int* in_sizes, int n_in,
                              void* d_out, int out_size, void* d_ws, size_t ws_size,
                              hipStream_t stream)
{
    const float* query = (const float*)d_in[0];
    const float* W1    = (const float*)d_in[1];
    const float* b1    = (const float*)d_in[2];
    const float* W2    = (const float*)d_in[3];
    const float* b2    = (const float*)d_in[4];
    const float* Wg    = (const float*)d_in[5];
    // d_in[6] = bg cancels under softmax+normalize; d_in[7] = topk (hardcoded 8)

    char* ws = (char*)d_ws;
    const size_t MB = 1024 * 1024;
    unsigned char* Q8   = (unsigned char*)(ws);                  // 8 MB
    unsigned char* W1T8 = (unsigned char*)(ws + 8 * MB);         // 4 MB
    unsigned char* W2T8 = (unsigned char*)(ws + 12 * MB);        // 4 MB
    float* logits   = (float*)(ws + 16 * MB);                    // 1 MB
    int*   cand     = (int*)  (ws + 17 * MB);                    // 16 KB
    float* ex_logit = (float*)(ws + 17 * MB + 16384);            // 16 KB
    float* ex_h     = (float*)(ws + 20 * MB);                    // 8 MB
    float* ex_x     = (float*)(ws + 28 * MB);                    // 8 MB

    prep_kernel<<<4352, 256, 0, stream>>>(query, W1, W2, Q8, W1T8, W2T8, logits);
    fused_mlp_kernel<<<4096, 256, 0, stream>>>(Q8, W1T8, W2T8, b1, b2, Wg, logits);
    topcand_kernel<<<64, 256, 0, stream>>>(logits, cand, ex_logit);
    exact_h_kernel<<<2048, 256, 0, stream>>>(query, W1, b1, cand, ex_h);
    exact_x_kernel<<<2048, 256, 0, stream>>>(ex_h, W2, b2, Wg, ex_x, ex_logit);
    final_kernel<<<64, 64, 0, stream>>>(ex_x, ex_logit, cand, (float*)d_out);
}

// Round 7
// 484.010 us; speedup vs baseline: 1.8159x; 1.2802x over previous
//
#include <hip/hip_runtime.h>
#include <hip/hip_bf16.h>
#include <cstdint>
#include <cstddef>

// Problem constants
#define NMEM 16
#define DDIM 512
#define BATCH 4
#define LSEQ 4096
#define ROWS 16384      // BATCH*LSEQ
#define NCAND 32        // fp8-noise safety: rank-8..32 gap ~4.5+ sigma
#define KTOP 8
#define QPAD 20

typedef __attribute__((ext_vector_type(4))) float f32x4;
typedef __attribute__((ext_vector_type(16))) float f32x16;
typedef __attribute__((ext_vector_type(8))) int int8v;

__device__ inline void gld16(const void* gptr, void* lptr) {
    __builtin_amdgcn_global_load_lds(
        (const __attribute__((address_space(1))) unsigned int*)gptr,
        (__attribute__((address_space(3))) unsigned int*)lptr,
        16, 0, 0);
}

__device__ inline float fast_tanh(float p) {
    p = fminf(fmaxf(p, -15.f), 15.f);
    float e = __expf(2.f * p);
    return (e - 1.f) / (e + 1.f);
}

// MX frag from a 128-B-row tile: chunks 2g^h, (2g+1)^h of row (h = swizzle key)
__device__ inline int8v load_frag(const unsigned char* Ts, int row, int g, int hs) {
    int h = (row >> hs) & 7;
    const int4* p0 = (const int4*)(Ts + row * 128 + (((2 * g) ^ h) << 4));
    const int4* p1 = (const int4*)(Ts + row * 128 + (((2 * g + 1) ^ h) << 4));
    int4 x = *p0, y = *p1;
    int8v v;
    v[0] = x.x; v[1] = x.y; v[2] = x.z; v[3] = x.w;
    v[4] = y.x; v[5] = y.y; v[6] = y.z; v[7] = y.w;
    return v;
}

// ---------- fused prep: Q->fp8, W1/W2 transpose->fp8, zero logits ----------
// grid: 2048 (Q) + 1024 (W1) + 1024 (W2) + 256 (logits zero) = 4352
__global__ __launch_bounds__(256)
void prep_kernel(const float* __restrict__ query,
                 const float* __restrict__ W1, const float* __restrict__ W2,
                 unsigned char* __restrict__ Q8,
                 unsigned char* __restrict__ W1T8, unsigned char* __restrict__ W2T8,
                 float* __restrict__ logits) {
    int blk = blockIdx.x, t = threadIdx.x;
    if (blk < 2048) {                       // Q convert: 16 els/thread
        size_t base = ((size_t)blk * 256 + t) * 16;
        const float4* in = (const float4*)(query + base);
        int4 o; int* op = (int*)&o;
        #pragma unroll
        for (int q = 0; q < 4; ++q) {
            float4 v = in[q];
            int lo = __builtin_amdgcn_cvt_pk_fp8_f32(v.x, v.y, 0, false);
            op[q] = __builtin_amdgcn_cvt_pk_fp8_f32(v.z, v.w, lo, true);
        }
        *(int4*)(Q8 + base) = o;
    } else if (blk < 4096) {                // W transpose+convert, 64x64 tiles
        __shared__ float tile[64][69];
        int bid = blk - 2048;               // 0..2047: 1024 per matrix
        const float* Win = W1; unsigned char* Wout = W1T8;
        if (bid >= 1024) { bid -= 1024; Win = W2; Wout = W2T8; }
        int n = bid >> 6, t64 = bid & 63;   // n in [0,16), 64 tiles of 64x64
        int dt = (t64 >> 3) << 6, jt = (t64 & 7) << 6;
        const float* inN = Win + (size_t)n * DDIM * DDIM;
        unsigned char* outN = Wout + (size_t)n * DDIM * DDIM;
        int rr = t >> 4, cc = (t & 15) * 4;
        #pragma unroll
        for (int pass = 0; pass < 4; ++pass) {
            int row = rr + pass * 16;
            float4 v = *(const float4*)(inN + (size_t)(dt + row) * DDIM + jt + cc);
            tile[row][cc] = v.x; tile[row][cc + 1] = v.y;
            tile[row][cc + 2] = v.z; tile[row][cc + 3] = v.w;
        }
        __syncthreads();
        #pragma unroll
        for (int pass = 0; pass < 4; ++pass) {
            int jl = rr + pass * 16;
            float f0 = tile[cc][jl], f1 = tile[cc + 1][jl];
            float f2 = tile[cc + 2][jl], f3 = tile[cc + 3][jl];
            int lo = __builtin_amdgcn_cvt_pk_fp8_f32(f0, f1, 0, false);
            int dw = __builtin_amdgcn_cvt_pk_fp8_f32(f2, f3, lo, true);
            *(int*)(outN + (size_t)(jt + jl) * DDIM + dt + cc) = dw;
        }
    } else {                                // zero logits (1 MB)
        int bid = blk - 4096;               // 0..255
        ((int4*)logits)[bid * 256 + t] = int4{0, 0, 0, 0};
    }
}

// ---------- fused MLP (v3): M=128 rows/block ----------
// grid 2048 = 128 m-tiles x 16 slots (n = id & 15 -> slot n, n+8 pinned per XCD).
// Block 256 = 4 waves (rh, ch); wave tile 64 rows x 64 cols per 128-col chunk,
// 2x2 of 32x32x64 MX MFMA. h (128x512 fp8) LDS-resident. LDS 80 KB -> 2 blocks/CU.
__global__ __launch_bounds__(256, 2)
void fused_mlp_kernel(const unsigned char* __restrict__ Q8,
                      const unsigned char* __restrict__ W1T8,
                      const unsigned char* __restrict__ W2T8,
                      const float* __restrict__ b1, const float* __restrict__ b2,
                      const float* __restrict__ Wg,
                      float* __restrict__ logits)
{
    __shared__ unsigned char hbuf[128 * 512];  // 64 KB fp8 h, chunk^row&7 swizzle
    __shared__ unsigned char Bs[128 * 128];    // 16 KB W-tile
    const int id = blockIdx.x;
    const int n = id & 15;
    const int m0 = (id >> 4) * 128;
    const int tid = threadIdx.x, lane = tid & 63, w = tid >> 6;
    const int rh = w >> 1, ch = w & 1;
    const int l31 = lane & 31, kh = lane >> 5;
    const unsigned char* W1n = W1T8 + (size_t)n * DDIM * DDIM;
    const unsigned char* W2n = W2T8 + (size_t)n * DDIM * DDIM;
    const float slope = 0.01f + 0.0125f * n;
    const unsigned char* Aq0 = Q8 + (size_t)(m0 + rh * 64 + l31) * DDIM + kh * 32;

    // ---- Phase A: h = leaky(Q W1 + b1) -> hbuf ----
    for (int n0 = 0; n0 < 4; ++n0) {
        f32x16 acc[2][2] = {};   // [rt][fc]
        const unsigned char* Bg = W1n + (size_t)(n0 * 128) * DDIM;
        for (int kt = 0; kt < 4; ++kt) {
            int8v av[2][2];      // [rt][ks]
            #pragma unroll
            for (int rt = 0; rt < 2; ++rt)
                #pragma unroll
                for (int ks = 0; ks < 2; ++ks) {
                    const unsigned char* ap = Aq0 + (size_t)rt * 32 * DDIM + kt * 128 + ks * 64;
                    int4 x = *(const int4*)ap;
                    int4 y = *(const int4*)(ap + 16);
                    av[rt][ks][0] = x.x; av[rt][ks][1] = x.y;
                    av[rt][ks][2] = x.z; av[rt][ks][3] = x.w;
                    av[rt][ks][4] = y.x; av[rt][ks][5] = y.y;
                    av[rt][ks][6] = y.z; av[rt][ks][7] = y.w;
                }
            #pragma unroll
            for (int i = 0; i < 4; ++i) {
                int c = i * 256 + tid;
                int row = c >> 3, chk = c & 7;
                gld16(Bg + (size_t)row * DDIM + kt * 128 + ((chk ^ (row & 7)) << 4),
                      &Bs[c * 16]);
            }
            __syncthreads();
            #pragma unroll
            for (int ks = 0; ks < 2; ++ks)
                #pragma unroll
                for (int fc = 0; fc < 2; ++fc) {
                    int8v bfr = load_frag(Bs, ch * 64 + fc * 32 + l31, ks * 2 + kh, 0);
                    #pragma unroll
                    for (int rt = 0; rt < 2; ++rt)
                        acc[rt][fc] = __builtin_amdgcn_mfma_scale_f32_32x32x64_f8f6f4(
                            av[rt][ks], bfr, acc[rt][fc], 0, 0, 0,
                            0x7F7F7F7F, 0, 0x7F7F7F7F);
                }
            __syncthreads();
        }
        #pragma unroll
        for (int fc = 0; fc < 2; ++fc) {
            int D = n0 * 128 + ch * 64 + fc * 32 + l31;
            float bias = b1[n * DDIM + D];
            #pragma unroll
            for (int rt = 0; rt < 2; ++rt)
                #pragma unroll
                for (int reg = 0; reg < 16; ++reg) {
                    int row = rh * 64 + rt * 32 + (reg & 3) + 8 * (reg >> 2) + 4 * kh;
                    float v = acc[rt][fc][reg] + bias;
                    v = v >= 0.f ? v : v * slope;
                    int pk = __builtin_amdgcn_cvt_pk_fp8_f32(v, v, 0, false);
                    hbuf[row * 512 + (((D >> 4) ^ (row & 7)) << 4) + (D & 15)]
                        = (unsigned char)(pk & 0xff);
                }
        }
    }

    // ---- Phase B: rowsum = sum_j tanh(h W2 + b2)[row][j] * Wg[j] ----
    float rowacc[2][16] = {};
    for (int n0 = 0; n0 < 4; ++n0) {
        f32x16 acc[2][2] = {};
        const unsigned char* Bg = W2n + (size_t)(n0 * 128) * DDIM;
        for (int kt = 0; kt < 4; ++kt) {
            #pragma unroll
            for (int i = 0; i < 4; ++i) {
                int c = i * 256 + tid;
                int row = c >> 3, chk = c & 7;
                gld16(Bg + (size_t)row * DDIM + kt * 128 + ((chk ^ (row & 7)) << 4),
                      &Bs[c * 16]);
            }
            __syncthreads();
            #pragma unroll
            for (int ks = 0; ks < 2; ++ks) {
                int8v av[2];
                #pragma unroll
                for (int rt = 0; rt < 2; ++rt) {
                    int hrow = rh * 64 + rt * 32 + l31, hq = hrow & 7;
                    int C0 = kt * 8 + ks * 4 + 2 * kh;
                    const int4* p0 = (const int4*)(hbuf + hrow * 512 + ((C0 ^ hq) << 4));
                    const int4* p1 = (const int4*)(hbuf + hrow * 512 + (((C0 + 1) ^ hq) << 4));
                    int4 x = *p0, y = *p1;
                    av[rt][0] = x.x; av[rt][1] = x.y; av[rt][2] = x.z; av[rt][3] = x.w;
                    av[rt][4] = y.x; av[rt][5] = y.y; av[rt][6] = y.z; av[rt][7] = y.w;
                }
                #pragma unroll
                for (int fc = 0; fc < 2; ++fc) {
                    int8v bfr = load_frag(Bs, ch * 64 + fc * 32 + l31, ks * 2 + kh, 0);
                    #pragma unroll
                    for (int rt = 0; rt < 2; ++rt)
                        acc[rt][fc] = __builtin_amdgcn_mfma_scale_f32_32x32x64_f8f6f4(
                            av[rt], bfr, acc[rt][fc], 0, 0, 0,
                            0x7F7F7F7F, 0, 0x7F7F7F7F);
                }
            }
            __syncthreads();
        }
        #pragma unroll
        for (int fc = 0; fc < 2; ++fc) {
            int j = n0 * 128 + ch * 64 + fc * 32 + l31;
            float bias = b2[n * DDIM + j];
            float wgv = Wg[n * DDIM + j];
            #pragma unroll
            for (int rt = 0; rt < 2; ++rt)
                #pragma unroll
                for (int reg = 0; reg < 16; ++reg)
                    rowacc[rt][reg] = fmaf(fast_tanh(acc[rt][fc][reg] + bias), wgv,
                                           rowacc[rt][reg]);
        }
    }
    #pragma unroll
    for (int sh = 1; sh < 32; sh <<= 1)
        #pragma unroll
        for (int rt = 0; rt < 2; ++rt)
            #pragma unroll
            for (int reg = 0; reg < 16; ++reg)
                rowacc[rt][reg] += __shfl_xor(rowacc[rt][reg], sh);
    if (l31 == 0) {
        float* Ln = logits + (size_t)n * ROWS + m0 + rh * 64 + 4 * kh;
        #pragma unroll
        for (int rt = 0; rt < 2; ++rt)
            #pragma unroll
            for (int reg = 0; reg < 16; ++reg)
                atomicAdd(&Ln[rt * 32 + (reg & 3) + 8 * (reg >> 2)], rowacc[rt][reg]);
    }
}

// ---------- topcand: per (n,b) top-32 of 4096 ----------
__global__ __launch_bounds__(256)
void topcand_kernel(const float* __restrict__ logits, int* __restrict__ cand,
                    float* __restrict__ ex_logit) {
    __shared__ float lv[LSEQ];
    __shared__ float cv[128];
    __shared__ int   ci[128];
    int p = blockIdx.x, n = p >> 2, b = p & 3;
    int t = threadIdx.x, lane = t & 63, w = t >> 6;
    const float* L = logits + (size_t)n * ROWS + (size_t)b * LSEQ;
    for (int i = t; i < LSEQ; i += 256) lv[i] = L[i];
    __syncthreads();
    // phase 1: each wave extracts top-32 of its 1024 (register-resident)
    float mv[16];
    int base = w * 1024;
    #pragma unroll
    for (int j = 0; j < 16; ++j) mv[j] = lv[base + j * 64 + lane];
    for (int rd = 0; rd < 32; ++rd) {
        float best = mv[0]; int bj = 0;
        #pragma unroll
        for (int j = 1; j < 16; ++j)
            if (mv[j] > best) { best = mv[j]; bj = j; }
        int bidx = base + bj * 64 + lane;
        float rv = best; int ridx = bidx;
        #pragma unroll
        for (int s = 1; s < 64; s <<= 1) {
            float ov = __shfl_xor(rv, s); int oi = __shfl_xor(ridx, s);
            if (ov > rv || (ov == rv && oi < ridx)) { rv = ov; ridx = oi; }
        }
        if (lane == 0) { cv[w * 32 + rd] = rv; ci[w * 32 + rd] = ridx; }
        if (ridx == bidx) mv[bj] = -1e30f;
    }
    __syncthreads();
    // phase 2: wave 0 merges 128 -> top-32; wave 1 zeroes ex_logit
    if (w == 0) {
        float v2[2]; int i2[2];
        #pragma unroll
        for (int k = 0; k < 2; ++k) { v2[k] = cv[k * 64 + lane]; i2[k] = ci[k * 64 + lane]; }
        for (int rd = 0; rd < 32; ++rd) {
            float best = v2[0]; int bi = i2[0]; int bk = 0;
            if (v2[1] > best || (v2[1] == best && i2[1] < bi)) { best = v2[1]; bi = i2[1]; bk = 1; }
            float rv = best; int ridx = bi;
            #pragma unroll
            for (int s = 1; s < 64; s <<= 1) {
                float ov = __shfl_xor(rv, s); int oi = __shfl_xor(ridx, s);
                if (ov > rv || (ov == rv && oi < ridx)) { rv = ov; ridx = oi; }
            }
            if (lane == 0) cand[p * NCAND + rd] = ridx;
            if (ridx == bi) v2[bk] = -1e30f;
        }
    } else if (w == 1) {
        if (lane < NCAND) ex_logit[p * NCAND + lane] = 0.f;
    }
}

// ---------- exact fp32 recompute: phase 1 (h) ----------
// grid 64p x 2ct x 8jc = 1024 blocks, 16 cands per block
__global__ __launch_bounds__(256)
void exact_h_kernel(const float* __restrict__ query,
                    const float* __restrict__ W1, const float* __restrict__ b1,
                    const int* __restrict__ cand, float* __restrict__ ex_h) {
    __shared__ float qs[DDIM][QPAD];
    __shared__ float hpart[4][16][64];
    int blk = blockIdx.x;
    int p = blk >> 4, r4 = blk & 15;
    int ct = r4 >> 3, jc = r4 & 7;
    int n = p >> 2, b = p & 3;
    int t = threadIdx.x, jj = t & 63, dg = t >> 6;
    int j = jc * 64 + jj;
    for (int c = 0; c < 16; ++c) {
        int li = cand[p * NCAND + ct * 16 + c];
        const float* qr = query + ((size_t)b * LSEQ + li) * DDIM;
        for (int d = t; d < DDIM; d += 256) qs[d][c] = qr[d];
    }
    __syncthreads();
    const float* W1n = W1 + (size_t)n * DDIM * DDIM;
    float acc[16] = {};
    for (int d = dg * 128; d < dg * 128 + 128; ++d) {
        float wvv = W1n[(size_t)d * DDIM + j];
        const float4* qv = (const float4*)&qs[d][0];
        #pragma unroll
        for (int c4 = 0; c4 < 4; ++c4) {
            float4 q4 = qv[c4];
            acc[c4 * 4 + 0] = fmaf(q4.x, wvv, acc[c4 * 4 + 0]);
            acc[c4 * 4 + 1] = fmaf(q4.y, wvv, acc[c4 * 4 + 1]);
            acc[c4 * 4 + 2] = fmaf(q4.z, wvv, acc[c4 * 4 + 2]);
            acc[c4 * 4 + 3] = fmaf(q4.w, wvv, acc[c4 * 4 + 3]);
        }
    }
    #pragma unroll
    for (int c = 0; c < 16; ++c) hpart[dg][c][jj] = acc[c];
    __syncthreads();
    const float slope = 0.01f + 0.0125f * n;
    float bias = b1[n * DDIM + j];
    for (int cc = dg; cc < 16; cc += 4) {
        float h = hpart[0][cc][jj] + hpart[1][cc][jj] + hpart[2][cc][jj]
                + hpart[3][cc][jj] + bias;
        h = h >= 0.f ? h : h * slope;
        ex_h[((size_t)p * NCAND + ct * 16 + cc) * DDIM + j] = h;
    }
}

// ---------- exact phase 2: x + exact logits ----------
__global__ __launch_bounds__(256)
void exact_x_kernel(const float* __restrict__ ex_h,
                    const float* __restrict__ W2, const float* __restrict__ b2,
                    const float* __restrict__ Wg,
                    float* __restrict__ ex_x, float* __restrict__ ex_logit) {
    __shared__ float hs[DDIM][QPAD];
    __shared__ float xpart[4][16][64];
    int blk = blockIdx.x;
    int p = blk >> 4, r4 = blk & 15;
    int ct = r4 >> 3, jc = r4 & 7;
    int n = p >> 2;
    int t = threadIdx.x, jj = t & 63, dg = t >> 6;
    int j = jc * 64 + jj;
    for (int c = 0; c < 16; ++c) {
        const float* hr = ex_h + ((size_t)p * NCAND + ct * 16 + c) * DDIM;
        for (int d = t; d < DDIM; d += 256) hs[d][c] = hr[d];
    }
    __syncthreads();
    const float* W2n = W2 + (size_t)n * DDIM * DDIM;
    float acc[16] = {};
    for (int d = dg * 128; d < dg * 128 + 128; ++d) {
        float wvv = W2n[(size_t)d * DDIM + j];
        const float4* hv = (const float4*)&hs[d][0];
        #pragma unroll
        for (int c4 = 0; c4 < 4; ++c4) {
            float4 h4 = hv[c4];
            acc[c4 * 4 + 0] = fmaf(h4.x, wvv, acc[c4 * 4 + 0]);
            acc[c4 * 4 + 1] = fmaf(h4.y, wvv, acc[c4 * 4 + 1]);
            acc[c4 * 4 + 2] = fmaf(h4.z, wvv, acc[c4 * 4 + 2]);
            acc[c4 * 4 + 3] = fmaf(h4.w, wvv, acc[c4 * 4 + 3]);
        }
    }
    #pragma unroll
    for (int c = 0; c < 16; ++c) xpart[dg][c][jj] = acc[c];
    __syncthreads();
    float bias = b2[n * DDIM + j];
    float wg = Wg[n * DDIM + j];
    for (int cc = dg; cc < 16; cc += 4) {
        float a = xpart[0][cc][jj] + xpart[1][cc][jj] + xpart[2][cc][jj]
                + xpart[3][cc][jj] + bias;
        float x = tanhf(a);
        ex_x[((size_t)p * NCAND + ct * 16 + cc) * DDIM + j] = x;
        float lp = x * wg;
        #pragma unroll
        for (int s = 1; s < 64; s <<= 1) lp += __shfl_xor(lp, s);
        if (jj == 0) atomicAdd(&ex_logit[p * NCAND + ct * 16 + cc], lp);
    }
}

// ---------- final: exact top-8 of 32, weight, combine, normalize ----------
__global__ __launch_bounds__(64)
void final_kernel(const float* __restrict__ ex_x, const float* __restrict__ ex_logit,
                  const int* __restrict__ cand, float* __restrict__ out)
{
    __shared__ float w8s[KTOP];
    __shared__ int   s8s[KTOP];
    int p = blockIdx.x, n = p >> 2, b = p & 3;
    int t = threadIdx.x;
    float myv = (t < NCAND) ? ex_logit[p * NCAND + t] : -1e30f;
    int myidx = (t < NCAND) ? cand[p * NCAND + t] : 0x7fffffff;
    float lmax = 0.f;
    for (int k = 0; k < KTOP; ++k) {
        float rv = myv; int ridx = myidx; int rl = t;
        #pragma unroll
        for (int s = 1; s < 64; s <<= 1) {
            float ov = __shfl_xor(rv, s); int oi = __shfl_xor(ridx, s); int ol = __shfl_xor(rl, s);
            if (ov > rv || (ov == rv && oi < ridx)) { rv = ov; ridx = oi; rl = ol; }
        }
        if (k == 0) lmax = rv;
        if (t == 0) { w8s[k] = __expf(rv - lmax); s8s[k] = rl; }
        if (t == rl) myv = -1e30f;
    }
    __syncthreads();
    float cvv[8];
    float sq = 0.f;
    int idx = 0;
    for (int d = t; d < DDIM; d += 64, ++idx) {
        float s = 0.f;
        #pragma unroll
        for (int k = 0; k < KTOP; ++k)
            s = fmaf(w8s[k], ex_x[((size_t)p * NCAND + s8s[k]) * DDIM + d], s);
        cvv[idx] = s;
        sq += s * s;
    }
    #pragma unroll
    for (int s = 1; s < 64; s <<= 1) sq += __shfl_xor(sq, s);
    float norm = fmaxf(sqrtf(sq), 1e-12f);
    idx = 0;
    for (int d = t; d < DDIM; d += 64, ++idx)
        out[((size_t)b * NMEM + n) * DDIM + d] = cvv[idx] / norm;
}

extern "C" void kernel_launch(void* const* d_in, const int* in_sizes, int n_in,
                              void* d_out, int out_size, void* d_ws, size_t ws_size,
                              hipStream_t stream)
{
    const float* query = (const float*)d_in[0];
    const float* W1    = (const float*)d_in[1];
    const float* b1    = (const float*)d_in[2];
    const float* W2    = (const float*)d_in[3];
    const float* b2    = (const float*)d_in[4];
    const float* Wg    = (const float*)d_in[5];
    // d_in[6] = bg cancels under softmax+normalize; d_in[7] = topk (hardcoded 8)

    char* ws = (char*)d_ws;
    const size_t MB = 1024 * 1024;
    unsigned char* Q8   = (unsigned char*)(ws);                  // 8 MB
    unsigned char* W1T8 = (unsigned char*)(ws + 8 * MB);         // 4 MB
    unsigned char* W2T8 = (unsigned char*)(ws + 12 * MB);        // 4 MB
    float* logits   = (float*)(ws + 16 * MB);                    // 1 MB
    int*   cand     = (int*)  (ws + 17 * MB);                    // 8 KB
    float* ex_logit = (float*)(ws + 17 * MB + 16384);            // 8 KB
    float* ex_h     = (float*)(ws + 20 * MB);                    // 4 MB
    float* ex_x     = (float*)(ws + 28 * MB);                    // 4 MB

    prep_kernel<<<4352, 256, 0, stream>>>(query, W1, W2, Q8, W1T8, W2T8, logits);
    fused_mlp_kernel<<<2048, 256, 0, stream>>>(Q8, W1T8, W2T8, b1, b2, Wg, logits);
    topcand_kernel<<<64, 256, 0, stream>>>(logits, cand, ex_logit);
    exact_h_kernel<<<1024, 256, 0, stream>>>(query, W1, b1, cand, ex_h);
    exact_x_kernel<<<1024, 256, 0, stream>>>(ex_h, W2, b2, Wg, ex_x, ex_logit);
    final_kernel<<<64, 64, 0, stream>>>(ex_x, ex_logit, cand, (float*)d_out);
}